// Round 7
// baseline (1167.186 us; speedup 1.0000x reference)
//
#include <hip/hip_runtime.h>
#include <hip/hip_bf16.h>
#include <cmath>

// ---------------------------------------------------------------------------
// BertLayer + top-2 MoE, MI355X. Round 12:
//  - fp32 GEMM body: 32x256 block kept, but A loaded via per-lane VMEM with
//    wave-uniform address (L1 broadcast) instead of s_load. Round-11's SMEM
//    path serialized on lgkmcnt (SMEM is unordered -> every s_load use forces
//    lgkmcnt(0), draining ds_reads; VALUBusy 57%). VMEM A sits on vmcnt
//    (ordered) -> B ds_reads pipeline freely. LDS port: B-only (768 cy) <
//    VALU (1024 cy) -> VALU-bound.
//  - QKV: K-split dropped (32-row blocks already give 1152 blocks = 4.5/CU);
//    reduce_qkv kernel deleted (-20us, -190MB traffic).
//  - Wo: ksplit 4 -> 2 (partials into dead q,k; ln_router sums 2).
//  - attn / experts / ln_router core unchanged (round-8 proven).
// ---------------------------------------------------------------------------

constexpr int cB = 8, cS = 512, cH = 768, cNH = 12, cDH = 64, cI = 3072, cE = 8;
constexpr int cT = cB * cS;                       // 4096 tokens
constexpr size_t TH = (size_t)cT * cH;            // 3,145,728

typedef __hip_bfloat16 bf16;
typedef __attribute__((ext_vector_type(8))) short s8v;   // 8 bf16 = 4 VGPRs
typedef __attribute__((ext_vector_type(4))) float f4v;   // MFMA accumulator

// ---- workspace layout (float units) ---------------------------------------
constexpr size_t SZ_WEXP     = (size_t)cE * cI * cH / 2;        // 9,437,184
constexpr size_t OFF_WUP_T   = 0;                               // [E][I][H] bf16
constexpr size_t OFF_WNEW_T  = OFF_WUP_T + SZ_WEXP;
constexpr size_t OFF_WDOWN_T = OFF_WNEW_T + SZ_WEXP;            // [E][H][I] bf16
constexpr size_t OFF_QKV     = OFF_WDOWN_T + SZ_WEXP;           // q,k,v,tmp fp32
constexpr size_t OFF_CTX     = OFF_QKV + 4 * TH;                // ctx fp32
constexpr size_t OFF_XLB     = OFF_CTX + TH;                    // xl bf16
constexpr size_t OFF_WGT     = OFF_XLB + TH / 2;                // 2T fp32
constexpr size_t OFF_COUNTS  = OFF_WGT + 2 * cT;                // int[16]
constexpr size_t OFF_LISTS   = OFF_COUNTS + 16;                 // int[E*T]
// act (bf16) aliases q/k/v/tmp region (dead once ln_router consumed partials).

// ---------------------------------------------------------------------------
__device__ __forceinline__ void glds16(const void* g, void* l) {
    __builtin_amdgcn_global_load_lds(
        (const __attribute__((address_space(1))) unsigned int*)g,
        (__attribute__((address_space(3))) unsigned int*)l, 16, 0, 0);
}

__global__ void init_counts_kernel(int* __restrict__ counts) {
    if (threadIdx.x < cE) counts[threadIdx.x] = 0;
}

// src [z][R][C] fp32 -> dst [z][C][R] bf16   (R,C multiples of 64)
__global__ __launch_bounds__(256) void transpose_bf16_kernel(
    const float* __restrict__ src, bf16* __restrict__ dst, int R, int C) {
    __shared__ float tile[64][65];
    const size_t zb = (size_t)blockIdx.z * R * C;
    const int r0 = blockIdx.y * 64, c0 = blockIdx.x * 64;
    const int t = threadIdx.x;
    const int lr = t >> 4, lc = (t & 15) * 4;
#pragma unroll
    for (int i = 0; i < 4; ++i) {
        float4 v = *(const float4*)(src + zb + (size_t)(r0 + lr + i * 16) * C + c0 + lc);
        tile[lr + i * 16][lc + 0] = v.x; tile[lr + i * 16][lc + 1] = v.y;
        tile[lr + i * 16][lc + 2] = v.z; tile[lr + i * 16][lc + 3] = v.w;
    }
    __syncthreads();
#pragma unroll
    for (int i = 0; i < 4; ++i) {
        int cr = lr + i * 16;
        bf16 o[4];
#pragma unroll
        for (int j = 0; j < 4; ++j) o[j] = (bf16)tile[lc + j][cr];
        *(uint2*)(dst + zb + (size_t)(c0 + cr) * R + r0 + lc) = *(uint2*)o;
    }
}

// ---------------------------------------------------------------------------
// fp32 GEMM, 32x256 block, BK=16, 4 waves x 8 wave-uniform rows, lane = 4 cols.
// A via per-lane VMEM broadcast (wave-uniform address -> 1 L1 fetch, vmcnt-
// ordered, no lgkm interaction). B staged via glds16 + 1 ds_read_b128/kk.
// K slice [kbeg,kend); bias iff addb. Accumulation order kk-sequential.
__device__ __forceinline__ void gemm_body_sg(
    const float* __restrict__ A, const float* __restrict__ B,
    const float* __restrict__ bias, float* __restrict__ C,
    int N, int K, int m0, int n0, int kbeg, int kend, bool addb) {
    __shared__ float Bs[16 * 256];   // [k][n] fp32, glds16 target
    const int t = threadIdx.x;
    const int wv = t >> 6, l = t & 63;
    const float* Ab = A + (size_t)(m0 + wv * 8) * K;   // wave-uniform (VMEM bcast)
    const float* gB = B + (size_t)(kbeg + wv * 4) * N + n0 + l * 4;
    float* dB = Bs + (wv * 4) * 256 + l * 4;
    float acc[8][4] = {};
    for (int k0 = kbeg; k0 < kend; k0 += 16) {
        glds16(gB, dB);
        glds16(gB + (size_t)N, dB + 256);
        glds16(gB + (size_t)2 * N, dB + 512);
        glds16(gB + (size_t)3 * N, dB + 768);
        __syncthreads();
#pragma unroll
        for (int q = 0; q < 4; ++q) {
            float4 a4[8];
#pragma unroll
            for (int r = 0; r < 8; ++r)
                a4[r] = *(const float4*)(Ab + (size_t)r * K + k0 + q * 4);
#pragma unroll
            for (int kq = 0; kq < 4; ++kq) {
                float4 b = *(const float4*)&Bs[(q * 4 + kq) * 256 + l * 4];
#pragma unroll
                for (int r = 0; r < 8; ++r) {
                    float av = (kq == 0) ? a4[r].x : (kq == 1) ? a4[r].y
                             : (kq == 2) ? a4[r].z : a4[r].w;
                    acc[r][0] += av * b.x;
                    acc[r][1] += av * b.y;
                    acc[r][2] += av * b.z;
                    acc[r][3] += av * b.w;
                }
            }
        }
        __syncthreads();
        gB += (size_t)16 * N;
    }
#pragma unroll
    for (int r = 0; r < 8; ++r) {
        int m = m0 + wv * 8 + r;
        float4 o;
        o.x = acc[r][0]; o.y = acc[r][1]; o.z = acc[r][2]; o.w = acc[r][3];
        if (addb) {
            o.x += bias[n0 + l * 4 + 0];
            o.y += bias[n0 + l * 4 + 1];
            o.z += bias[n0 + l * 4 + 2];
            o.w += bias[n0 + l * 4 + 3];
        }
        *(float4*)(C + (size_t)m * N + n0 + l * 4) = o;
    }
}

// QKV: grid (3,128,3) flat 1152 = 8 XCD chunks x (16 m-tiles x 3 n x 3 proj).
// No K-split (full K=768). m-tile fastest within chunk.
__global__ __launch_bounds__(256) void gemm_qkv_kernel(
    const float* __restrict__ A,
    const float* __restrict__ Wq, const float* __restrict__ Wk,
    const float* __restrict__ Wv,
    const float* __restrict__ bq, const float* __restrict__ bk,
    const float* __restrict__ bv,
    float* __restrict__ q, float* __restrict__ k, float* __restrict__ v) {
    const int f = blockIdx.x + 3 * blockIdx.y + 384 * blockIdx.z;  // 0..1151
    const int xcd = f & 7, p = f >> 3;       // p: 0..143
    const int yl = p & 15;                   // m-tile within chunk (fastest)
    const int n  = (p >> 4) % 3;             // n-tile (256 cols)
    const int proj = p / 48;                 // 0..2
    const int y  = xcd * 16 + yl;            // 0..127
    const float* B = (proj == 0) ? Wq : (proj == 1) ? Wk : Wv;
    const float* bias = (proj == 0) ? bq : (proj == 1) ? bk : bv;
    float* C = (proj == 0) ? q : (proj == 1) ? k : v;
    gemm_body_sg(A, B, bias, C, cH, cH, y * 32, n * 256, 0, cH, true);
}

// Wo: grid (3,128,2) flat 768, ksplit=2 into dead partial buffers (q,k);
// ln_router sums. Same XCD chunk-swizzle.
__global__ __launch_bounds__(256) void gemm_wo_kernel(
    const float* __restrict__ A, const float* __restrict__ W,
    const float* __restrict__ bias,
    float* __restrict__ p0, float* __restrict__ p1) {
    const int f = blockIdx.x + 3 * blockIdx.y + 384 * blockIdx.z;  // 0..767
    const int xcd = f & 7, p = f >> 3;       // p: 0..95
    const int yl = p & 15;
    const int n  = (p >> 4) % 3;
    const int ks = p / 48;                   // 0..1
    const int y  = xcd * 16 + yl;
    gemm_body_sg(A, W, bias, ks ? p1 : p0, cH, cH, y * 32, n * 256,
                 ks * 384, ks * 384 + 384, ks == 0);
}

// ---------------------------------------------------------------------------
// Flash-style fp32 attention (round-4/8 proven, plain mapping).
__global__ __launch_bounds__(256) void attn_kernel(
    const float* __restrict__ q, const float* __restrict__ k,
    const float* __restrict__ v, float* __restrict__ ctx) {
    __shared__ float sQ[64][68];
    __shared__ float sKV[64][68];
    __shared__ float sS[64][68];
    __shared__ float sM[64], sL[64], sAl[64];
    const int q0 = blockIdx.x * 64, h = blockIdx.y, b = blockIdx.z;
    const int t = threadIdx.x;
    const int lr = t >> 2, lq = (t & 3) * 16;
    {
        const float* gq = q + (size_t)(b * cS + q0 + lr) * cH + h * cDH + lq;
#pragma unroll
        for (int j = 0; j < 4; ++j) {
            float4 x = *(const float4*)(gq + j * 4);
            x.x *= 0.125f; x.y *= 0.125f; x.z *= 0.125f; x.w *= 0.125f;
            *(float4*)&sQ[lr][lq + j * 4] = x;
        }
    }
    if (t < 64) { sM[t] = -1e30f; sL[t] = 0.f; }
    const int c0 = t & 15, rr = (t >> 4) * 4;
    const int d4 = (t & 15) * 4, rp = (t >> 4) * 4;
    const int sr = t >> 2, sc = (t & 3) * 16;
    float4 o_acc[4];
#pragma unroll
    for (int i = 0; i < 4; ++i) o_acc[i] = make_float4(0.f, 0.f, 0.f, 0.f);

    for (int kt = 0; kt < 8; ++kt) {
        float4 kreg[4];
        {
            const float* gk = k + (size_t)(b * cS + kt * 64 + lr) * cH + h * cDH + lq;
#pragma unroll
            for (int j = 0; j < 4; ++j) kreg[j] = *(const float4*)(gk + j * 4);
        }
        __syncthreads();
#pragma unroll
        for (int j = 0; j < 4; ++j) *(float4*)&sKV[lr][lq + j * 4] = kreg[j];
        __syncthreads();
        float accS[4][4] = {};
#pragma unroll
        for (int d = 0; d < 64; d += 4) {
            float4 qv[4], kv[4];
#pragma unroll
            for (int i = 0; i < 4; ++i) qv[i] = *(const float4*)&sQ[rr + i][d];
#pragma unroll
            for (int j = 0; j < 4; ++j) kv[j] = *(const float4*)&sKV[c0 + 16 * j][d];
#pragma unroll
            for (int i = 0; i < 4; ++i)
#pragma unroll
                for (int j = 0; j < 4; ++j)
                    accS[i][j] += qv[i].x * kv[j].x + qv[i].y * kv[j].y +
                                  qv[i].z * kv[j].z + qv[i].w * kv[j].w;
        }
#pragma unroll
        for (int i = 0; i < 4; ++i)
#pragma unroll
            for (int j = 0; j < 4; ++j) sS[rr + i][c0 + 16 * j] = accS[i][j];
        float4 vreg[4];
        {
            const float* gv = v + (size_t)(b * cS + kt * 64 + lr) * cH + h * cDH + lq;
#pragma unroll
            for (int j = 0; j < 4; ++j) vreg[j] = *(const float4*)(gv + j * 4);
        }
        __syncthreads();
        {
            float4 s[4];
#pragma unroll
            for (int j = 0; j < 4; ++j) s[j] = *(const float4*)&sS[sr][sc + j * 4];
            float m = -1e30f;
#pragma unroll
            for (int j = 0; j < 4; ++j)
                m = fmaxf(m, fmaxf(fmaxf(s[j].x, s[j].y), fmaxf(s[j].z, s[j].w)));
            m = fmaxf(m, __shfl_xor(m, 1));
            m = fmaxf(m, __shfl_xor(m, 2));
            float m_old = sM[sr];
            float m_new = fmaxf(m_old, m);
            float sum = 0.f;
#pragma unroll
            for (int j = 0; j < 4; ++j) {
                s[j].x = __expf(s[j].x - m_new); s[j].y = __expf(s[j].y - m_new);
                s[j].z = __expf(s[j].z - m_new); s[j].w = __expf(s[j].w - m_new);
                sum += s[j].x + s[j].y + s[j].z + s[j].w;
                *(float4*)&sS[sr][sc + j * 4] = s[j];
            }
            sum += __shfl_xor(sum, 1);
            sum += __shfl_xor(sum, 2);
            if ((t & 3) == 0) {
                float alpha = __expf(m_old - m_new);
                sAl[sr] = alpha;
                sM[sr] = m_new;
                sL[sr] = sL[sr] * alpha + sum;
            }
        }
#pragma unroll
        for (int j = 0; j < 4; ++j) *(float4*)&sKV[lr][lq + j * 4] = vreg[j];
        __syncthreads();
#pragma unroll
        for (int i = 0; i < 4; ++i) {
            float al = sAl[rp + i];
            o_acc[i].x *= al; o_acc[i].y *= al; o_acc[i].z *= al; o_acc[i].w *= al;
        }
        for (int kk4 = 0; kk4 < 64; kk4 += 4) {
            float4 pv[4], vv[4];
#pragma unroll
            for (int i = 0; i < 4; ++i) pv[i] = *(const float4*)&sS[rp + i][kk4];
#pragma unroll
            for (int j = 0; j < 4; ++j) vv[j] = *(const float4*)&sKV[kk4 + j][d4];
#pragma unroll
            for (int i = 0; i < 4; ++i) {
                o_acc[i].x += pv[i].x * vv[0].x + pv[i].y * vv[1].x +
                              pv[i].z * vv[2].x + pv[i].w * vv[3].x;
                o_acc[i].y += pv[i].x * vv[0].y + pv[i].y * vv[1].y +
                              pv[i].z * vv[2].y + pv[i].w * vv[3].y;
                o_acc[i].z += pv[i].x * vv[0].z + pv[i].y * vv[1].z +
                              pv[i].z * vv[2].z + pv[i].w * vv[3].z;
                o_acc[i].w += pv[i].x * vv[0].w + pv[i].y * vv[1].w +
                              pv[i].z * vv[2].w + pv[i].w * vv[3].w;
            }
        }
    }
    __syncthreads();
#pragma unroll
    for (int i = 0; i < 4; ++i) {
        float inv = 1.0f / sL[rp + i];
        float4 o = o_acc[i];
        o.x *= inv; o.y *= inv; o.z *= inv; o.w *= inv;
        *(float4*)(ctx + (size_t)(b * cS + q0 + rp + i) * cH + h * cDH + d4) = o;
    }
}

__device__ __forceinline__ float block_reduce_sum(float v, float* red) {
#pragma unroll
    for (int o = 32; o; o >>= 1) v += __shfl_xor(v, o);
    __syncthreads();
    if ((threadIdx.x & 63) == 0) red[threadIdx.x >> 6] = v;
    __syncthreads();
    return red[0] + red[1] + red[2] + red[3];
}

// ---------------------------------------------------------------------------
// LN1 + LN2 + router, fp32 (selection-exact). Dense = two K-split partials.
__global__ __launch_bounds__(256) void ln_router_kernel(
    const float* __restrict__ dense0, const float* __restrict__ dense1,
    const float* __restrict__ resid,
    const float* __restrict__ g1, const float* __restrict__ b1,
    const float* __restrict__ g2, const float* __restrict__ b2,
    const float* __restrict__ Wr, const float* __restrict__ br,
    float* __restrict__ out, bf16* __restrict__ xlb,
    float* __restrict__ out_logits, float* __restrict__ wgt,
    int* __restrict__ counts, int* __restrict__ lists) {
    __shared__ float red[4];
    __shared__ float lred[4][8];
    const int t = blockIdx.x, tid = threadIdx.x;
    const size_t base = (size_t)t * cH;
    float v[3], s = 0.f;
#pragma unroll
    for (int i = 0; i < 3; ++i) {
        size_t ix = base + tid + 256 * i;
        v[i] = dense0[ix] + dense1[ix] + resid[ix];
        s += v[i];
    }
    const float mean = block_reduce_sum(s, red) * (1.0f / cH);
    float vs = 0.f;
#pragma unroll
    for (int i = 0; i < 3; ++i) { float d = v[i] - mean; vs += d * d; }
    const float rstd = rsqrtf(block_reduce_sum(vs, red) * (1.0f / cH) + 1e-12f);
    float a[3], s2 = 0.f;
#pragma unroll
    for (int i = 0; i < 3; ++i) {
        a[i] = (v[i] - mean) * rstd * g1[tid + 256 * i] + b1[tid + 256 * i];
        out[base + tid + 256 * i] = a[i];
        s2 += a[i];
    }
    const float mean2 = block_reduce_sum(s2, red) * (1.0f / cH);
    float vs2 = 0.f;
#pragma unroll
    for (int i = 0; i < 3; ++i) { float d = a[i] - mean2; vs2 += d * d; }
    const float rstd2 = rsqrtf(block_reduce_sum(vs2, red) * (1.0f / cH) + 1e-12f);
    float xl[3];
#pragma unroll
    for (int i = 0; i < 3; ++i) {
        xl[i] = (a[i] - mean2) * rstd2 * g2[tid + 256 * i] + b2[tid + 256 * i];
        xlb[base + tid + 256 * i] = (bf16)xl[i];
    }
    float lg[cE] = {};
#pragma unroll
    for (int i = 0; i < 3; ++i) {
        const float* wr = Wr + (size_t)(tid + 256 * i) * cE;
#pragma unroll
        for (int e = 0; e < cE; ++e) lg[e] += xl[i] * wr[e];
    }
#pragma unroll
    for (int e = 0; e < cE; ++e)
#pragma unroll
        for (int o = 32; o; o >>= 1) lg[e] += __shfl_xor(lg[e], o);
    if ((tid & 63) == 0)
#pragma unroll
        for (int e = 0; e < cE; ++e) lred[tid >> 6][e] = lg[e];
    __syncthreads();
    if (tid == 0) {
        float logits[cE];
#pragma unroll
        for (int e = 0; e < cE; ++e) {
            logits[e] = lred[0][e] + lred[1][e] + lred[2][e] + lred[3][e] + br[e];
            out_logits[(size_t)t * cE + e] = logits[e];
        }
        int i0 = 0;
        for (int e = 1; e < cE; ++e) if (logits[e] > logits[i0]) i0 = e;
        int i1 = (i0 == 0) ? 1 : 0;
        for (int e = 0; e < cE; ++e)
            if (e != i0 && logits[e] > logits[i1]) i1 = e;
        float e1 = __expf(logits[i1] - logits[i0]);
        float w0 = 1.0f / (1.0f + e1);
        float w1 = e1 * w0;
        wgt[t * 2 + 0] = w0;
        wgt[t * 2 + 1] = w1;
        int p0 = atomicAdd(&counts[i0], 1);
        lists[i0 * cT + p0] = t * 2 + 0;
        int p1 = atomicAdd(&counts[i1], 1);
        lists[i1 * cT + p1] = t * 2 + 1;
    }
}

// ---------------------------------------------------------------------------
// Expert up, 128x64 tile: per-wave 64x32 dual-acc (64 AGPR total). Round-8 map.
__global__ __launch_bounds__(256) void expert_up_mfma_kernel(
    const bf16* __restrict__ xlb,
    const bf16* __restrict__ WupT, const bf16* __restrict__ WnewT,
    const float* __restrict__ b_up, const float* __restrict__ b_new,
    const int* __restrict__ counts, const int* __restrict__ lists,
    bf16* __restrict__ act) {
    const int e = blockIdx.z;
    const int cnt = counts[e];
    const int m0 = blockIdx.y * 128;
    if (m0 >= cnt) return;
    const int n0 = blockIdx.x * 64;
    __shared__ short sA[128 * 32], sB1[64 * 32], sB2[64 * 32];
    __shared__ int rowa[128];
    const int t = threadIdx.x;
    if (t < 128) {
        int idx = m0 + t;
        rowa[t] = (idx < cnt) ? lists[e * cT + idx] : -1;
    }
    __syncthreads();
    const int lane = t & 63, w = t >> 6;
    const int wm = (w >> 1) * 64, wn = (w & 1) * 32;
    const int rA0 = t >> 2, kc8 = (t & 3) * 8;
    int a0 = rowa[rA0], a1 = rowa[rA0 + 64];
    const bf16* gA0 = xlb + (size_t)(a0 < 0 ? 0 : (a0 >> 1)) * cH + kc8;
    const bf16* gA1 = xlb + (size_t)(a1 < 0 ? 0 : (a1 >> 1)) * cH + kc8;
    const bf16* B1 = WupT + (size_t)e * cI * cH;
    const bf16* B2 = WnewT + (size_t)e * cI * cH;
    const bf16* gB1 = B1 + (size_t)(n0 + rA0) * cH + kc8;
    const bf16* gB2 = B2 + (size_t)(n0 + rA0) * cH + kc8;
    short* dA0 = sA + t * 8;   short* dA1 = sA + (t + 256) * 8;
    short* dB1 = sB1 + t * 8;  short* dB2 = sB2 + t * 8;
    f4v zero = {0.f, 0.f, 0.f, 0.f};
    f4v acc1[4][2], acc2[4][2];
#pragma unroll
    for (int i = 0; i < 4; ++i)
#pragma unroll
        for (int j = 0; j < 2; ++j) { acc1[i][j] = zero; acc2[i][j] = zero; }
    const int fr = lane & 15, kg = (lane >> 4) * 8;
    for (int kk = 0; kk < cH; kk += 32) {
        glds16(gA0, dA0); glds16(gA1, dA1);
        glds16(gB1, dB1); glds16(gB2, dB2);
        __syncthreads();
        s8v af[4], bf1[2], bf2[2];
#pragma unroll
        for (int i = 0; i < 4; ++i)
            af[i] = *(const s8v*)(sA + (wm + i * 16 + fr) * 32 + kg);
#pragma unroll
        for (int j = 0; j < 2; ++j) {
            bf1[j] = *(const s8v*)(sB1 + (wn + j * 16 + fr) * 32 + kg);
            bf2[j] = *(const s8v*)(sB2 + (wn + j * 16 + fr) * 32 + kg);
        }
#pragma unroll
        for (int mi = 0; mi < 4; ++mi)
#pragma unroll
            for (int ni = 0; ni < 2; ++ni) {
                acc1[mi][ni] = __builtin_amdgcn_mfma_f32_16x16x32_bf16(
                    af[mi], bf1[ni], acc1[mi][ni], 0, 0, 0);
                acc2[mi][ni] = __builtin_amdgcn_mfma_f32_16x16x32_bf16(
                    af[mi], bf2[ni], acc2[mi][ni], 0, 0, 0);
            }
        __syncthreads();
        gA0 += 32; gA1 += 32; gB1 += 32; gB2 += 32;
    }
    const int cn = lane & 15, rq = (lane >> 4) * 4;
#pragma unroll
    for (int mi = 0; mi < 4; ++mi)
#pragma unroll
        for (int r = 0; r < 4; ++r) {
            int ml = wm + mi * 16 + rq + r;
            int a = rowa[ml];
            if (a < 0) continue;
            bf16* orow = act + (size_t)a * cI + n0 + wn;
#pragma unroll
            for (int ni = 0; ni < 2; ++ni) {
                int nl = ni * 16 + cn;
                float up = acc1[mi][ni][r] + b_up[e * cI + n0 + wn + nl];
                float nw = acc2[mi][ni][r] + b_new[e * cI + n0 + wn + nl];
                float g = 0.5f * up * (1.0f + erff(up * 0.70710678118654752f));
                orow[nl] = (bf16)(g * nw);
            }
        }
}

// Expert down (128x128, 64 AGPR): out += w*(act@WdownT+b). Round-8 map.
__global__ __launch_bounds__(256) void expert_down_mfma_kernel(
    const bf16* __restrict__ act, const bf16* __restrict__ WdownT,
    const float* __restrict__ b_down,
    const int* __restrict__ counts, const int* __restrict__ lists,
    const float* __restrict__ wgt, float* __restrict__ out) {
    const int e = blockIdx.z;
    const int cnt = counts[e];
    const int m0 = blockIdx.y * 128;
    if (m0 >= cnt) return;
    const int n0 = blockIdx.x * 128;
    __shared__ short sA[128 * 32], sB[128 * 32];
    __shared__ int rowa[128];
    const int t = threadIdx.x;
    if (t < 128) {
        int idx = m0 + t;
        rowa[t] = (idx < cnt) ? lists[e * cT + idx] : -1;
    }
    __syncthreads();
    const int lane = t & 63, w = t >> 6;
    const int wm = (w >> 1) * 64, wn = (w & 1) * 64;
    const int rA0 = t >> 2, kc8 = (t & 3) * 8;
    int a0 = rowa[rA0], a1 = rowa[rA0 + 64];
    const bf16* gA0 = act + (size_t)(a0 < 0 ? 0 : a0) * cI + kc8;
    const bf16* gA1 = act + (size_t)(a1 < 0 ? 0 : a1) * cI + kc8;
    const bf16* BT = WdownT + (size_t)e * cH * cI;
    const bf16* gB0 = BT + (size_t)(n0 + rA0) * cI + kc8;
    const bf16* gB1 = BT + (size_t)(n0 + rA0 + 64) * cI + kc8;
    short* dA0 = sA + t * 8;       short* dA1 = sA + (t + 256) * 8;
    short* dB0 = sB + t * 8;       short* dB1 = sB + (t + 256) * 8;
    f4v zero = {0.f, 0.f, 0.f, 0.f};
    f4v acc[4][4];
#pragma unroll
    for (int i = 0; i < 4; ++i)
#pragma unroll
        for (int j = 0; j < 4; ++j) acc[i][j] = zero;
    const int fr = lane & 15, kg = (lane >> 4) * 8;
    for (int kk = 0; kk < cI; kk += 32) {
        glds16(gA0, dA0); glds16(gA1, dA1);
        glds16(gB0, dB0); glds16(gB1, dB1);
        __syncthreads();
        s8v af[4], bf[4];
#pragma unroll
        for (int i = 0; i < 4; ++i) af[i] = *(const s8v*)(sA + (wm + i * 16 + fr) * 32 + kg);
#pragma unroll
        for (int i = 0; i < 4; ++i) bf[i] = *(const s8v*)(sB + (wn + i * 16 + fr) * 32 + kg);
#pragma unroll
        for (int mi = 0; mi < 4; ++mi)
#pragma unroll
            for (int ni = 0; ni < 4; ++ni)
                acc[mi][ni] = __builtin_amdgcn_mfma_f32_16x16x32_bf16(
                    af[mi], bf[ni], acc[mi][ni], 0, 0, 0);
        __syncthreads();
        gA0 += 32; gA1 += 32; gB0 += 32; gB1 += 32;
    }
    const int cn = lane & 15, rq = (lane >> 4) * 4;
#pragma unroll
    for (int mi = 0; mi < 4; ++mi)
#pragma unroll
        for (int r = 0; r < 4; ++r) {
            int ml = wm + mi * 16 + rq + r;
            int a = rowa[ml];
            if (a < 0) continue;
            int token = a >> 1;
            float wv = wgt[a];
#pragma unroll
            for (int ni = 0; ni < 4; ++ni) {
                int n = n0 + wn + ni * 16 + cn;
                atomicAdd(&out[(size_t)token * cH + n],
                          wv * (acc[mi][ni][r] + b_down[e * cH + n]));
            }
        }
}

// ---------------------------------------------------------------------------
extern "C" void kernel_launch(void* const* d_in, const int* in_sizes, int n_in,
                              void* d_out, int out_size, void* d_ws, size_t ws_size,
                              hipStream_t stream) {
    const float* x      = (const float*)d_in[0];
    const float* Wq     = (const float*)d_in[1];
    const float* bq     = (const float*)d_in[2];
    const float* Wk     = (const float*)d_in[3];
    const float* bk     = (const float*)d_in[4];
    const float* Wv     = (const float*)d_in[5];
    const float* bv     = (const float*)d_in[6];
    const float* Wo     = (const float*)d_in[7];
    const float* bo     = (const float*)d_in[8];
    const float* ln1g   = (const float*)d_in[9];
    const float* ln1b   = (const float*)d_in[10];
    const float* ln2g   = (const float*)d_in[11];
    const float* ln2b   = (const float*)d_in[12];
    const float* Wr     = (const float*)d_in[13];
    const float* br     = (const float*)d_in[14];
    const float* W_up   = (const float*)d_in[15];
    const float* b_up   = (const float*)d_in[16];
    const float* W_new  = (const float*)d_in[17];
    const float* b_new  = (const float*)d_in[18];
    const float* W_down = (const float*)d_in[19];
    const float* b_down = (const float*)d_in[20];

    float* out = (float*)d_out;
    float* ws  = (float*)d_ws;

    bf16* WupT   = (bf16*)(ws + OFF_WUP_T);
    bf16* WnewT  = (bf16*)(ws + OFF_WNEW_T);
    bf16* WdownT = (bf16*)(ws + OFF_WDOWN_T);
    float* q     = ws + OFF_QKV;
    float* k     = ws + OFF_QKV + TH;
    float* v     = ws + OFF_QKV + 2 * TH;
    float* tmp   = ws + OFF_QKV + 3 * TH;
    bf16* act    = (bf16*)(ws + OFF_QKV);   // aliases q/k/v/tmp (dead by then)
    float* ctx   = ws + OFF_CTX;
    bf16* xlb    = (bf16*)(ws + OFF_XLB);
    float* wgt   = ws + OFF_WGT;
    int* counts  = (int*)(ws + OFF_COUNTS);
    int* lists   = (int*)(ws + OFF_LISTS);
    (void)tmp;

    init_counts_kernel<<<1, 64, 0, stream>>>(counts);

    // expert weight transpose+convert
    transpose_bf16_kernel<<<dim3(48, 12, cE), 256, 0, stream>>>(W_up, WupT, cH, cI);
    transpose_bf16_kernel<<<dim3(48, 12, cE), 256, 0, stream>>>(W_new, WnewT, cH, cI);
    transpose_bf16_kernel<<<dim3(12, 48, cE), 256, 0, stream>>>(W_down, WdownT, cI, cH);

    // fp32 pre-router path (selection-exact), 32x256 VMEM-broadcast-A body.
    gemm_qkv_kernel<<<dim3(3, 128, 3), 256, 0, stream>>>(
        x, Wq, Wk, Wv, bq, bk, bv, q, k, v);
    attn_kernel<<<dim3(cS / 64, cNH, cB), 256, 0, stream>>>(q, k, v, ctx);
    // Wo ksplit=2: partials into dead q,k; summed inside ln_router
    gemm_wo_kernel<<<dim3(3, 128, 2), 256, 0, stream>>>(ctx, Wo, bo, q, k);
    ln_router_kernel<<<cT, 256, 0, stream>>>(
        q, k, x, ln1g, ln1b, ln2g, ln2b, Wr, br,
        out, xlb, out + TH, wgt, counts, lists);

    // bf16 MFMA experts (scatter-add into out)
    expert_up_mfma_kernel<<<dim3(cI / 64, cT / 128, cE), 256, 0, stream>>>(
        xlb, WupT, WnewT, b_up, b_new, counts, lists, act);
    expert_down_mfma_kernel<<<dim3(cH / 128, cT / 128, cE), 256, 0, stream>>>(
        act, WdownT, b_down, counts, lists, wgt, out);
}

// Round 8
// 1062.665 us; speedup vs baseline: 1.0984x; 1.0984x over previous
//
#include <hip/hip_runtime.h>
#include <hip/hip_bf16.h>
#include <cmath>

// ---------------------------------------------------------------------------
// BertLayer + top-2 MoE, MI355X. Round 13 (consolidation):
//  - fp32 GEMM body: round-11 s_load variant (32x256, wave-uniform A rows via
//    readfirstlane -> SMEM; B via glds16 + 1 ds_read_b128/kk; 0 bank
//    conflicts; measured 187us / VALUBusy 57%). Round-12's VMEM-broadcast A
//    REVERTED (320us: 32 latency-exposed loads/K-step at 2.8 waves/SIMD).
//  - QKV: no K-split (1152 blocks = 4.5/CU), reduce_qkv deleted (-20us).
//    Single-pass full-K accumulation validated by round 12 (absmax 0.03125).
//  - Wo: ksplit=2 into dead q,k; ln_router sums 2 partials (round-12 proven).
//  - attn / experts / ln_router core: round-8 proven, untouched.
// ---------------------------------------------------------------------------

constexpr int cB = 8, cS = 512, cH = 768, cNH = 12, cDH = 64, cI = 3072, cE = 8;
constexpr int cT = cB * cS;                       // 4096 tokens
constexpr size_t TH = (size_t)cT * cH;            // 3,145,728

typedef __hip_bfloat16 bf16;
typedef __attribute__((ext_vector_type(8))) short s8v;   // 8 bf16 = 4 VGPRs
typedef __attribute__((ext_vector_type(4))) float f4v;   // MFMA accumulator

// ---- workspace layout (float units) ---------------------------------------
constexpr size_t SZ_WEXP     = (size_t)cE * cI * cH / 2;        // 9,437,184
constexpr size_t OFF_WUP_T   = 0;                               // [E][I][H] bf16
constexpr size_t OFF_WNEW_T  = OFF_WUP_T + SZ_WEXP;
constexpr size_t OFF_WDOWN_T = OFF_WNEW_T + SZ_WEXP;            // [E][H][I] bf16
constexpr size_t OFF_QKV     = OFF_WDOWN_T + SZ_WEXP;           // q,k,v,tmp fp32
constexpr size_t OFF_CTX     = OFF_QKV + 4 * TH;                // ctx fp32
constexpr size_t OFF_XLB     = OFF_CTX + TH;                    // xl bf16
constexpr size_t OFF_WGT     = OFF_XLB + TH / 2;                // 2T fp32
constexpr size_t OFF_COUNTS  = OFF_WGT + 2 * cT;                // int[16]
constexpr size_t OFF_LISTS   = OFF_COUNTS + 16;                 // int[E*T]
// act (bf16) aliases q/k/v/tmp region (dead once ln_router consumed partials).

// ---------------------------------------------------------------------------
__device__ __forceinline__ void glds16(const void* g, void* l) {
    __builtin_amdgcn_global_load_lds(
        (const __attribute__((address_space(1))) unsigned int*)g,
        (__attribute__((address_space(3))) unsigned int*)l, 16, 0, 0);
}

__global__ void init_counts_kernel(int* __restrict__ counts) {
    if (threadIdx.x < cE) counts[threadIdx.x] = 0;
}

// src [z][R][C] fp32 -> dst [z][C][R] bf16   (R,C multiples of 64)
__global__ __launch_bounds__(256) void transpose_bf16_kernel(
    const float* __restrict__ src, bf16* __restrict__ dst, int R, int C) {
    __shared__ float tile[64][65];
    const size_t zb = (size_t)blockIdx.z * R * C;
    const int r0 = blockIdx.y * 64, c0 = blockIdx.x * 64;
    const int t = threadIdx.x;
    const int lr = t >> 4, lc = (t & 15) * 4;
#pragma unroll
    for (int i = 0; i < 4; ++i) {
        float4 v = *(const float4*)(src + zb + (size_t)(r0 + lr + i * 16) * C + c0 + lc);
        tile[lr + i * 16][lc + 0] = v.x; tile[lr + i * 16][lc + 1] = v.y;
        tile[lr + i * 16][lc + 2] = v.z; tile[lr + i * 16][lc + 3] = v.w;
    }
    __syncthreads();
#pragma unroll
    for (int i = 0; i < 4; ++i) {
        int cr = lr + i * 16;
        bf16 o[4];
#pragma unroll
        for (int j = 0; j < 4; ++j) o[j] = (bf16)tile[lc + j][cr];
        *(uint2*)(dst + zb + (size_t)(c0 + cr) * R + r0 + lc) = *(uint2*)o;
    }
}

// ---------------------------------------------------------------------------
// fp32 GEMM, 32x256 block, BK=16, 4 waves x 8 wave-uniform rows, lane = 4 cols.
// A read via scalar loads (uniform base via readfirstlane -> SMEM pipe),
// B staged via glds16 + 1 ds_read_b128/kk. Zero LDS bank conflicts (measured).
// K slice [kbeg,kend); bias iff addb. Accumulation kk-sequential.
__device__ __forceinline__ void gemm_body_sg(
    const float* __restrict__ A, const float* __restrict__ B,
    const float* __restrict__ bias, float* __restrict__ C,
    int N, int K, int m0, int n0, int kbeg, int kend, bool addb) {
    __shared__ float Bs[16 * 256];   // [k][n] fp32, glds16 target
    const int t = threadIdx.x;
    const int wv = t >> 6, l = t & 63;
    const int wu = __builtin_amdgcn_readfirstlane(wv);   // force uniform
    const float* Ab = A + (size_t)(m0 + wu * 8) * K;     // wave-uniform base
    const float* gB = B + (size_t)(kbeg + wv * 4) * N + n0 + l * 4;
    float* dB = Bs + (wv * 4) * 256 + l * 4;
    float acc[8][4] = {};
    for (int k0 = kbeg; k0 < kend; k0 += 16) {
        glds16(gB, dB);
        glds16(gB + (size_t)N, dB + 256);
        glds16(gB + (size_t)2 * N, dB + 512);
        glds16(gB + (size_t)3 * N, dB + 768);
        __syncthreads();
#pragma unroll
        for (int q = 0; q < 4; ++q) {
            float4 a4[8];
#pragma unroll
            for (int r = 0; r < 8; ++r)
                a4[r] = *(const float4*)(Ab + (size_t)r * K + k0 + q * 4);
#pragma unroll
            for (int kq = 0; kq < 4; ++kq) {
                float4 b = *(const float4*)&Bs[(q * 4 + kq) * 256 + l * 4];
#pragma unroll
                for (int r = 0; r < 8; ++r) {
                    float av = (kq == 0) ? a4[r].x : (kq == 1) ? a4[r].y
                             : (kq == 2) ? a4[r].z : a4[r].w;
                    acc[r][0] += av * b.x;
                    acc[r][1] += av * b.y;
                    acc[r][2] += av * b.z;
                    acc[r][3] += av * b.w;
                }
            }
        }
        __syncthreads();
        gB += (size_t)16 * N;
    }
#pragma unroll
    for (int r = 0; r < 8; ++r) {
        int m = m0 + wu * 8 + r;
        float4 o;
        o.x = acc[r][0]; o.y = acc[r][1]; o.z = acc[r][2]; o.w = acc[r][3];
        if (addb) {
            o.x += bias[n0 + l * 4 + 0];
            o.y += bias[n0 + l * 4 + 1];
            o.z += bias[n0 + l * 4 + 2];
            o.w += bias[n0 + l * 4 + 3];
        }
        *(float4*)(C + (size_t)m * N + n0 + l * 4) = o;
    }
}

// QKV: grid (3,128,3) flat 1152 = 8 XCD chunks x (16 m-tiles x 3 n x 3 proj).
// No K-split (full K=768). m-tile fastest within chunk.
__global__ __launch_bounds__(256) void gemm_qkv_kernel(
    const float* __restrict__ A,
    const float* __restrict__ Wq, const float* __restrict__ Wk,
    const float* __restrict__ Wv,
    const float* __restrict__ bq, const float* __restrict__ bk,
    const float* __restrict__ bv,
    float* __restrict__ q, float* __restrict__ k, float* __restrict__ v) {
    const int f = blockIdx.x + 3 * blockIdx.y + 384 * blockIdx.z;  // 0..1151
    const int xcd = f & 7, p = f >> 3;       // p: 0..143
    const int yl = p & 15;                   // m-tile within chunk (fastest)
    const int n  = (p >> 4) % 3;             // n-tile (256 cols)
    const int proj = p / 48;                 // 0..2
    const int y  = xcd * 16 + yl;            // 0..127
    const float* B = (proj == 0) ? Wq : (proj == 1) ? Wk : Wv;
    const float* bias = (proj == 0) ? bq : (proj == 1) ? bk : bv;
    float* C = (proj == 0) ? q : (proj == 1) ? k : v;
    gemm_body_sg(A, B, bias, C, cH, cH, y * 32, n * 256, 0, cH, true);
}

// Wo: grid (3,128,2) flat 768, ksplit=2 into dead partial buffers (q,k);
// ln_router sums. Same XCD chunk-swizzle.
__global__ __launch_bounds__(256) void gemm_wo_kernel(
    const float* __restrict__ A, const float* __restrict__ W,
    const float* __restrict__ bias,
    float* __restrict__ p0, float* __restrict__ p1) {
    const int f = blockIdx.x + 3 * blockIdx.y + 384 * blockIdx.z;  // 0..767
    const int xcd = f & 7, p = f >> 3;       // p: 0..95
    const int yl = p & 15;
    const int n  = (p >> 4) % 3;
    const int ks = p / 48;                   // 0..1
    const int y  = xcd * 16 + yl;
    gemm_body_sg(A, W, bias, ks ? p1 : p0, cH, cH, y * 32, n * 256,
                 ks * 384, ks * 384 + 384, ks == 0);
}

// ---------------------------------------------------------------------------
// Flash-style fp32 attention (round-4/8 proven, plain mapping).
__global__ __launch_bounds__(256) void attn_kernel(
    const float* __restrict__ q, const float* __restrict__ k,
    const float* __restrict__ v, float* __restrict__ ctx) {
    __shared__ float sQ[64][68];
    __shared__ float sKV[64][68];
    __shared__ float sS[64][68];
    __shared__ float sM[64], sL[64], sAl[64];
    const int q0 = blockIdx.x * 64, h = blockIdx.y, b = blockIdx.z;
    const int t = threadIdx.x;
    const int lr = t >> 2, lq = (t & 3) * 16;
    {
        const float* gq = q + (size_t)(b * cS + q0 + lr) * cH + h * cDH + lq;
#pragma unroll
        for (int j = 0; j < 4; ++j) {
            float4 x = *(const float4*)(gq + j * 4);
            x.x *= 0.125f; x.y *= 0.125f; x.z *= 0.125f; x.w *= 0.125f;
            *(float4*)&sQ[lr][lq + j * 4] = x;
        }
    }
    if (t < 64) { sM[t] = -1e30f; sL[t] = 0.f; }
    const int c0 = t & 15, rr = (t >> 4) * 4;
    const int d4 = (t & 15) * 4, rp = (t >> 4) * 4;
    const int sr = t >> 2, sc = (t & 3) * 16;
    float4 o_acc[4];
#pragma unroll
    for (int i = 0; i < 4; ++i) o_acc[i] = make_float4(0.f, 0.f, 0.f, 0.f);

    for (int kt = 0; kt < 8; ++kt) {
        float4 kreg[4];
        {
            const float* gk = k + (size_t)(b * cS + kt * 64 + lr) * cH + h * cDH + lq;
#pragma unroll
            for (int j = 0; j < 4; ++j) kreg[j] = *(const float4*)(gk + j * 4);
        }
        __syncthreads();
#pragma unroll
        for (int j = 0; j < 4; ++j) *(float4*)&sKV[lr][lq + j * 4] = kreg[j];
        __syncthreads();
        float accS[4][4] = {};
#pragma unroll
        for (int d = 0; d < 64; d += 4) {
            float4 qv[4], kv[4];
#pragma unroll
            for (int i = 0; i < 4; ++i) qv[i] = *(const float4*)&sQ[rr + i][d];
#pragma unroll
            for (int j = 0; j < 4; ++j) kv[j] = *(const float4*)&sKV[c0 + 16 * j][d];
#pragma unroll
            for (int i = 0; i < 4; ++i)
#pragma unroll
                for (int j = 0; j < 4; ++j)
                    accS[i][j] += qv[i].x * kv[j].x + qv[i].y * kv[j].y +
                                  qv[i].z * kv[j].z + qv[i].w * kv[j].w;
        }
#pragma unroll
        for (int i = 0; i < 4; ++i)
#pragma unroll
            for (int j = 0; j < 4; ++j) sS[rr + i][c0 + 16 * j] = accS[i][j];
        float4 vreg[4];
        {
            const float* gv = v + (size_t)(b * cS + kt * 64 + lr) * cH + h * cDH + lq;
#pragma unroll
            for (int j = 0; j < 4; ++j) vreg[j] = *(const float4*)(gv + j * 4);
        }
        __syncthreads();
        {
            float4 s[4];
#pragma unroll
            for (int j = 0; j < 4; ++j) s[j] = *(const float4*)&sS[sr][sc + j * 4];
            float m = -1e30f;
#pragma unroll
            for (int j = 0; j < 4; ++j)
                m = fmaxf(m, fmaxf(fmaxf(s[j].x, s[j].y), fmaxf(s[j].z, s[j].w)));
            m = fmaxf(m, __shfl_xor(m, 1));
            m = fmaxf(m, __shfl_xor(m, 2));
            float m_old = sM[sr];
            float m_new = fmaxf(m_old, m);
            float sum = 0.f;
#pragma unroll
            for (int j = 0; j < 4; ++j) {
                s[j].x = __expf(s[j].x - m_new); s[j].y = __expf(s[j].y - m_new);
                s[j].z = __expf(s[j].z - m_new); s[j].w = __expf(s[j].w - m_new);
                sum += s[j].x + s[j].y + s[j].z + s[j].w;
                *(float4*)&sS[sr][sc + j * 4] = s[j];
            }
            sum += __shfl_xor(sum, 1);
            sum += __shfl_xor(sum, 2);
            if ((t & 3) == 0) {
                float alpha = __expf(m_old - m_new);
                sAl[sr] = alpha;
                sM[sr] = m_new;
                sL[sr] = sL[sr] * alpha + sum;
            }
        }
#pragma unroll
        for (int j = 0; j < 4; ++j) *(float4*)&sKV[lr][lq + j * 4] = vreg[j];
        __syncthreads();
#pragma unroll
        for (int i = 0; i < 4; ++i) {
            float al = sAl[rp + i];
            o_acc[i].x *= al; o_acc[i].y *= al; o_acc[i].z *= al; o_acc[i].w *= al;
        }
        for (int kk4 = 0; kk4 < 64; kk4 += 4) {
            float4 pv[4], vv[4];
#pragma unroll
            for (int i = 0; i < 4; ++i) pv[i] = *(const float4*)&sS[rp + i][kk4];
#pragma unroll
            for (int j = 0; j < 4; ++j) vv[j] = *(const float4*)&sKV[kk4 + j][d4];
#pragma unroll
            for (int i = 0; i < 4; ++i) {
                o_acc[i].x += pv[i].x * vv[0].x + pv[i].y * vv[1].x +
                              pv[i].z * vv[2].x + pv[i].w * vv[3].x;
                o_acc[i].y += pv[i].x * vv[0].y + pv[i].y * vv[1].y +
                              pv[i].z * vv[2].y + pv[i].w * vv[3].y;
                o_acc[i].z += pv[i].x * vv[0].z + pv[i].y * vv[1].z +
                              pv[i].z * vv[2].z + pv[i].w * vv[3].z;
                o_acc[i].w += pv[i].x * vv[0].w + pv[i].y * vv[1].w +
                              pv[i].z * vv[2].w + pv[i].w * vv[3].w;
            }
        }
    }
    __syncthreads();
#pragma unroll
    for (int i = 0; i < 4; ++i) {
        float inv = 1.0f / sL[rp + i];
        float4 o = o_acc[i];
        o.x *= inv; o.y *= inv; o.z *= inv; o.w *= inv;
        *(float4*)(ctx + (size_t)(b * cS + q0 + rp + i) * cH + h * cDH + d4) = o;
    }
}

__device__ __forceinline__ float block_reduce_sum(float v, float* red) {
#pragma unroll
    for (int o = 32; o; o >>= 1) v += __shfl_xor(v, o);
    __syncthreads();
    if ((threadIdx.x & 63) == 0) red[threadIdx.x >> 6] = v;
    __syncthreads();
    return red[0] + red[1] + red[2] + red[3];
}

// ---------------------------------------------------------------------------
// LN1 + LN2 + router, fp32 (selection-exact). Dense = two K-split partials.
__global__ __launch_bounds__(256) void ln_router_kernel(
    const float* __restrict__ dense0, const float* __restrict__ dense1,
    const float* __restrict__ resid,
    const float* __restrict__ g1, const float* __restrict__ b1,
    const float* __restrict__ g2, const float* __restrict__ b2,
    const float* __restrict__ Wr, const float* __restrict__ br,
    float* __restrict__ out, bf16* __restrict__ xlb,
    float* __restrict__ out_logits, float* __restrict__ wgt,
    int* __restrict__ counts, int* __restrict__ lists) {
    __shared__ float red[4];
    __shared__ float lred[4][8];
    const int t = blockIdx.x, tid = threadIdx.x;
    const size_t base = (size_t)t * cH;
    float v[3], s = 0.f;
#pragma unroll
    for (int i = 0; i < 3; ++i) {
        size_t ix = base + tid + 256 * i;
        v[i] = dense0[ix] + dense1[ix] + resid[ix];
        s += v[i];
    }
    const float mean = block_reduce_sum(s, red) * (1.0f / cH);
    float vs = 0.f;
#pragma unroll
    for (int i = 0; i < 3; ++i) { float d = v[i] - mean; vs += d * d; }
    const float rstd = rsqrtf(block_reduce_sum(vs, red) * (1.0f / cH) + 1e-12f);
    float a[3], s2 = 0.f;
#pragma unroll
    for (int i = 0; i < 3; ++i) {
        a[i] = (v[i] - mean) * rstd * g1[tid + 256 * i] + b1[tid + 256 * i];
        out[base + tid + 256 * i] = a[i];
        s2 += a[i];
    }
    const float mean2 = block_reduce_sum(s2, red) * (1.0f / cH);
    float vs2 = 0.f;
#pragma unroll
    for (int i = 0; i < 3; ++i) { float d = a[i] - mean2; vs2 += d * d; }
    const float rstd2 = rsqrtf(block_reduce_sum(vs2, red) * (1.0f / cH) + 1e-12f);
    float xl[3];
#pragma unroll
    for (int i = 0; i < 3; ++i) {
        xl[i] = (a[i] - mean2) * rstd2 * g2[tid + 256 * i] + b2[tid + 256 * i];
        xlb[base + tid + 256 * i] = (bf16)xl[i];
    }
    float lg[cE] = {};
#pragma unroll
    for (int i = 0; i < 3; ++i) {
        const float* wr = Wr + (size_t)(tid + 256 * i) * cE;
#pragma unroll
        for (int e = 0; e < cE; ++e) lg[e] += xl[i] * wr[e];
    }
#pragma unroll
    for (int e = 0; e < cE; ++e)
#pragma unroll
        for (int o = 32; o; o >>= 1) lg[e] += __shfl_xor(lg[e], o);
    if ((tid & 63) == 0)
#pragma unroll
        for (int e = 0; e < cE; ++e) lred[tid >> 6][e] = lg[e];
    __syncthreads();
    if (tid == 0) {
        float logits[cE];
#pragma unroll
        for (int e = 0; e < cE; ++e) {
            logits[e] = lred[0][e] + lred[1][e] + lred[2][e] + lred[3][e] + br[e];
            out_logits[(size_t)t * cE + e] = logits[e];
        }
        int i0 = 0;
        for (int e = 1; e < cE; ++e) if (logits[e] > logits[i0]) i0 = e;
        int i1 = (i0 == 0) ? 1 : 0;
        for (int e = 0; e < cE; ++e)
            if (e != i0 && logits[e] > logits[i1]) i1 = e;
        float e1 = __expf(logits[i1] - logits[i0]);
        float w0 = 1.0f / (1.0f + e1);
        float w1 = e1 * w0;
        wgt[t * 2 + 0] = w0;
        wgt[t * 2 + 1] = w1;
        int p0 = atomicAdd(&counts[i0], 1);
        lists[i0 * cT + p0] = t * 2 + 0;
        int p1 = atomicAdd(&counts[i1], 1);
        lists[i1 * cT + p1] = t * 2 + 1;
    }
}

// ---------------------------------------------------------------------------
// Expert up, 128x64 tile: per-wave 64x32 dual-acc (64 AGPR total). Round-8 map.
__global__ __launch_bounds__(256) void expert_up_mfma_kernel(
    const bf16* __restrict__ xlb,
    const bf16* __restrict__ WupT, const bf16* __restrict__ WnewT,
    const float* __restrict__ b_up, const float* __restrict__ b_new,
    const int* __restrict__ counts, const int* __restrict__ lists,
    bf16* __restrict__ act) {
    const int e = blockIdx.z;
    const int cnt = counts[e];
    const int m0 = blockIdx.y * 128;
    if (m0 >= cnt) return;
    const int n0 = blockIdx.x * 64;
    __shared__ short sA[128 * 32], sB1[64 * 32], sB2[64 * 32];
    __shared__ int rowa[128];
    const int t = threadIdx.x;
    if (t < 128) {
        int idx = m0 + t;
        rowa[t] = (idx < cnt) ? lists[e * cT + idx] : -1;
    }
    __syncthreads();
    const int lane = t & 63, w = t >> 6;
    const int wm = (w >> 1) * 64, wn = (w & 1) * 32;
    const int rA0 = t >> 2, kc8 = (t & 3) * 8;
    int a0 = rowa[rA0], a1 = rowa[rA0 + 64];
    const bf16* gA0 = xlb + (size_t)(a0 < 0 ? 0 : (a0 >> 1)) * cH + kc8;
    const bf16* gA1 = xlb + (size_t)(a1 < 0 ? 0 : (a1 >> 1)) * cH + kc8;
    const bf16* B1 = WupT + (size_t)e * cI * cH;
    const bf16* B2 = WnewT + (size_t)e * cI * cH;
    const bf16* gB1 = B1 + (size_t)(n0 + rA0) * cH + kc8;
    const bf16* gB2 = B2 + (size_t)(n0 + rA0) * cH + kc8;
    short* dA0 = sA + t * 8;   short* dA1 = sA + (t + 256) * 8;
    short* dB1 = sB1 + t * 8;  short* dB2 = sB2 + t * 8;
    f4v zero = {0.f, 0.f, 0.f, 0.f};
    f4v acc1[4][2], acc2[4][2];
#pragma unroll
    for (int i = 0; i < 4; ++i)
#pragma unroll
        for (int j = 0; j < 2; ++j) { acc1[i][j] = zero; acc2[i][j] = zero; }
    const int fr = lane & 15, kg = (lane >> 4) * 8;
    for (int kk = 0; kk < cH; kk += 32) {
        glds16(gA0, dA0); glds16(gA1, dA1);
        glds16(gB1, dB1); glds16(gB2, dB2);
        __syncthreads();
        s8v af[4], bf1[2], bf2[2];
#pragma unroll
        for (int i = 0; i < 4; ++i)
            af[i] = *(const s8v*)(sA + (wm + i * 16 + fr) * 32 + kg);
#pragma unroll
        for (int j = 0; j < 2; ++j) {
            bf1[j] = *(const s8v*)(sB1 + (wn + j * 16 + fr) * 32 + kg);
            bf2[j] = *(const s8v*)(sB2 + (wn + j * 16 + fr) * 32 + kg);
        }
#pragma unroll
        for (int mi = 0; mi < 4; ++mi)
#pragma unroll
            for (int ni = 0; ni < 2; ++ni) {
                acc1[mi][ni] = __builtin_amdgcn_mfma_f32_16x16x32_bf16(
                    af[mi], bf1[ni], acc1[mi][ni], 0, 0, 0);
                acc2[mi][ni] = __builtin_amdgcn_mfma_f32_16x16x32_bf16(
                    af[mi], bf2[ni], acc2[mi][ni], 0, 0, 0);
            }
        __syncthreads();
        gA0 += 32; gA1 += 32; gB1 += 32; gB2 += 32;
    }
    const int cn = lane & 15, rq = (lane >> 4) * 4;
#pragma unroll
    for (int mi = 0; mi < 4; ++mi)
#pragma unroll
        for (int r = 0; r < 4; ++r) {
            int ml = wm + mi * 16 + rq + r;
            int a = rowa[ml];
            if (a < 0) continue;
            bf16* orow = act + (size_t)a * cI + n0 + wn;
#pragma unroll
            for (int ni = 0; ni < 2; ++ni) {
                int nl = ni * 16 + cn;
                float up = acc1[mi][ni][r] + b_up[e * cI + n0 + wn + nl];
                float nw = acc2[mi][ni][r] + b_new[e * cI + n0 + wn + nl];
                float g = 0.5f * up * (1.0f + erff(up * 0.70710678118654752f));
                orow[nl] = (bf16)(g * nw);
            }
        }
}

// Expert down (128x128, 64 AGPR): out += w*(act@WdownT+b). Round-8 map.
__global__ __launch_bounds__(256) void expert_down_mfma_kernel(
    const bf16* __restrict__ act, const bf16* __restrict__ WdownT,
    const float* __restrict__ b_down,
    const int* __restrict__ counts, const int* __restrict__ lists,
    const float* __restrict__ wgt, float* __restrict__ out) {
    const int e = blockIdx.z;
    const int cnt = counts[e];
    const int m0 = blockIdx.y * 128;
    if (m0 >= cnt) return;
    const int n0 = blockIdx.x * 128;
    __shared__ short sA[128 * 32], sB[128 * 32];
    __shared__ int rowa[128];
    const int t = threadIdx.x;
    if (t < 128) {
        int idx = m0 + t;
        rowa[t] = (idx < cnt) ? lists[e * cT + idx] : -1;
    }
    __syncthreads();
    const int lane = t & 63, w = t >> 6;
    const int wm = (w >> 1) * 64, wn = (w & 1) * 64;
    const int rA0 = t >> 2, kc8 = (t & 3) * 8;
    int a0 = rowa[rA0], a1 = rowa[rA0 + 64];
    const bf16* gA0 = act + (size_t)(a0 < 0 ? 0 : a0) * cI + kc8;
    const bf16* gA1 = act + (size_t)(a1 < 0 ? 0 : a1) * cI + kc8;
    const bf16* BT = WdownT + (size_t)e * cH * cI;
    const bf16* gB0 = BT + (size_t)(n0 + rA0) * cI + kc8;
    const bf16* gB1 = BT + (size_t)(n0 + rA0 + 64) * cI + kc8;
    short* dA0 = sA + t * 8;       short* dA1 = sA + (t + 256) * 8;
    short* dB0 = sB + t * 8;       short* dB1 = sB + (t + 256) * 8;
    f4v zero = {0.f, 0.f, 0.f, 0.f};
    f4v acc[4][4];
#pragma unroll
    for (int i = 0; i < 4; ++i)
#pragma unroll
        for (int j = 0; j < 4; ++j) acc[i][j] = zero;
    const int fr = lane & 15, kg = (lane >> 4) * 8;
    for (int kk = 0; kk < cI; kk += 32) {
        glds16(gA0, dA0); glds16(gA1, dA1);
        glds16(gB0, dB0); glds16(gB1, dB1);
        __syncthreads();
        s8v af[4], bf[4];
#pragma unroll
        for (int i = 0; i < 4; ++i) af[i] = *(const s8v*)(sA + (wm + i * 16 + fr) * 32 + kg);
#pragma unroll
        for (int i = 0; i < 4; ++i) bf[i] = *(const s8v*)(sB + (wn + i * 16 + fr) * 32 + kg);
#pragma unroll
        for (int mi = 0; mi < 4; ++mi)
#pragma unroll
            for (int ni = 0; ni < 4; ++ni)
                acc[mi][ni] = __builtin_amdgcn_mfma_f32_16x16x32_bf16(
                    af[mi], bf[ni], acc[mi][ni], 0, 0, 0);
        __syncthreads();
        gA0 += 32; gA1 += 32; gB0 += 32; gB1 += 32;
    }
    const int cn = lane & 15, rq = (lane >> 4) * 4;
#pragma unroll
    for (int mi = 0; mi < 4; ++mi)
#pragma unroll
        for (int r = 0; r < 4; ++r) {
            int ml = wm + mi * 16 + rq + r;
            int a = rowa[ml];
            if (a < 0) continue;
            int token = a >> 1;
            float wv = wgt[a];
#pragma unroll
            for (int ni = 0; ni < 4; ++ni) {
                int n = n0 + wn + ni * 16 + cn;
                atomicAdd(&out[(size_t)token * cH + n],
                          wv * (acc[mi][ni][r] + b_down[e * cH + n]));
            }
        }
}

// ---------------------------------------------------------------------------
extern "C" void kernel_launch(void* const* d_in, const int* in_sizes, int n_in,
                              void* d_out, int out_size, void* d_ws, size_t ws_size,
                              hipStream_t stream) {
    const float* x      = (const float*)d_in[0];
    const float* Wq     = (const float*)d_in[1];
    const float* bq     = (const float*)d_in[2];
    const float* Wk     = (const float*)d_in[3];
    const float* bk     = (const float*)d_in[4];
    const float* Wv     = (const float*)d_in[5];
    const float* bv     = (const float*)d_in[6];
    const float* Wo     = (const float*)d_in[7];
    const float* bo     = (const float*)d_in[8];
    const float* ln1g   = (const float*)d_in[9];
    const float* ln1b   = (const float*)d_in[10];
    const float* ln2g   = (const float*)d_in[11];
    const float* ln2b   = (const float*)d_in[12];
    const float* Wr     = (const float*)d_in[13];
    const float* br     = (const float*)d_in[14];
    const float* W_up   = (const float*)d_in[15];
    const float* b_up   = (const float*)d_in[16];
    const float* W_new  = (const float*)d_in[17];
    const float* b_new  = (const float*)d_in[18];
    const float* W_down = (const float*)d_in[19];
    const float* b_down = (const float*)d_in[20];

    float* out = (float*)d_out;
    float* ws  = (float*)d_ws;

    bf16* WupT   = (bf16*)(ws + OFF_WUP_T);
    bf16* WnewT  = (bf16*)(ws + OFF_WNEW_T);
    bf16* WdownT = (bf16*)(ws + OFF_WDOWN_T);
    float* q     = ws + OFF_QKV;
    float* k     = ws + OFF_QKV + TH;
    float* v     = ws + OFF_QKV + 2 * TH;
    float* tmp   = ws + OFF_QKV + 3 * TH;
    bf16* act    = (bf16*)(ws + OFF_QKV);   // aliases q/k/v/tmp (dead by then)
    float* ctx   = ws + OFF_CTX;
    bf16* xlb    = (bf16*)(ws + OFF_XLB);
    float* wgt   = ws + OFF_WGT;
    int* counts  = (int*)(ws + OFF_COUNTS);
    int* lists   = (int*)(ws + OFF_LISTS);
    (void)tmp;

    init_counts_kernel<<<1, 64, 0, stream>>>(counts);

    // expert weight transpose+convert
    transpose_bf16_kernel<<<dim3(48, 12, cE), 256, 0, stream>>>(W_up, WupT, cH, cI);
    transpose_bf16_kernel<<<dim3(48, 12, cE), 256, 0, stream>>>(W_new, WnewT, cH, cI);
    transpose_bf16_kernel<<<dim3(12, 48, cE), 256, 0, stream>>>(W_down, WdownT, cI, cH);

    // fp32 pre-router path (selection-exact), 32x256 s_load-A body.
    gemm_qkv_kernel<<<dim3(3, 128, 3), 256, 0, stream>>>(
        x, Wq, Wk, Wv, bq, bk, bv, q, k, v);
    attn_kernel<<<dim3(cS / 64, cNH, cB), 256, 0, stream>>>(q, k, v, ctx);
    // Wo ksplit=2: partials into dead q,k; summed inside ln_router
    gemm_wo_kernel<<<dim3(3, 128, 2), 256, 0, stream>>>(ctx, Wo, bo, q, k);
    ln_router_kernel<<<cT, 256, 0, stream>>>(
        q, k, x, ln1g, ln1b, ln2g, ln2b, Wr, br,
        out, xlb, out + TH, wgt, counts, lists);

    // bf16 MFMA experts (scatter-add into out)
    expert_up_mfma_kernel<<<dim3(cI / 64, cT / 128, cE), 256, 0, stream>>>(
        xlb, WupT, WnewT, b_up, b_new, counts, lists, act);
    expert_down_mfma_kernel<<<dim3(cH / 128, cT / 128, cE), 256, 0, stream>>>(
        act, WdownT, b_down, counts, lists, wgt, out);
}

// Round 9
// 1024.859 us; speedup vs baseline: 1.1389x; 1.0369x over previous
//
#include <hip/hip_runtime.h>
#include <hip/hip_bf16.h>
#include <cmath>

// ---------------------------------------------------------------------------
// BertLayer + top-2 MoE, MI355X. Round 14:
//  - fp32 path: round-11 EXACT config restored (best measured, 1045.6us):
//    32x256 s_load body, QKV ksplit2 grid 2304 (body needs ~9 blk/CU TLP —
//    round 13 proved 1152 blocks => +40us), reduce_qkv, Wo ksplit4.
//  - Experts: BK 32 -> 64 as two [*][32] sub-tiles (sA[2][128][32] etc).
//    Fragment-read geometry identical to proven BK=32 code; staging stays
//    glds16-linear; barriers per K halved (16 -> 32 MFMA between barriers).
//    MFMA order kk-sequential => bit-exact. LDS 16.5 -> 32.5KB (4 blk/CU).
// ---------------------------------------------------------------------------

constexpr int cB = 8, cS = 512, cH = 768, cNH = 12, cDH = 64, cI = 3072, cE = 8;
constexpr int cT = cB * cS;                       // 4096 tokens
constexpr size_t TH = (size_t)cT * cH;            // 3,145,728

typedef __hip_bfloat16 bf16;
typedef __attribute__((ext_vector_type(8))) short s8v;   // 8 bf16 = 4 VGPRs
typedef __attribute__((ext_vector_type(4))) float f4v;   // MFMA accumulator

// ---- workspace layout (float units) ---------------------------------------
constexpr size_t SZ_WEXP     = (size_t)cE * cI * cH / 2;        // 9,437,184
constexpr size_t OFF_WUP_T   = 0;                               // [E][I][H] bf16
constexpr size_t OFF_WNEW_T  = OFF_WUP_T + SZ_WEXP;
constexpr size_t OFF_WDOWN_T = OFF_WNEW_T + SZ_WEXP;            // [E][H][I] bf16
constexpr size_t OFF_QKV     = OFF_WDOWN_T + SZ_WEXP;           // q,k,v,tmp fp32
constexpr size_t OFF_CTX     = OFF_QKV + 4 * TH;                // ctx fp32
constexpr size_t OFF_XLB     = OFF_CTX + TH;                    // xl bf16
constexpr size_t OFF_WGT     = OFF_XLB + TH / 2;                // 2T fp32
constexpr size_t OFF_COUNTS  = OFF_WGT + 2 * cT;                // int[16]
constexpr size_t OFF_LISTS   = OFF_COUNTS + 16;                 // int[E*T]
// act (bf16) aliases q/k/v/tmp region (dead once ln_router consumed partials).
// d_out is used as v1 K-split scratch before ln_router rewrites it fully.

// ---------------------------------------------------------------------------
__device__ __forceinline__ void glds16(const void* g, void* l) {
    __builtin_amdgcn_global_load_lds(
        (const __attribute__((address_space(1))) unsigned int*)g,
        (__attribute__((address_space(3))) unsigned int*)l, 16, 0, 0);
}

__global__ void init_counts_kernel(int* __restrict__ counts) {
    if (threadIdx.x < cE) counts[threadIdx.x] = 0;
}

// src [z][R][C] fp32 -> dst [z][C][R] bf16   (R,C multiples of 64)
__global__ __launch_bounds__(256) void transpose_bf16_kernel(
    const float* __restrict__ src, bf16* __restrict__ dst, int R, int C) {
    __shared__ float tile[64][65];
    const size_t zb = (size_t)blockIdx.z * R * C;
    const int r0 = blockIdx.y * 64, c0 = blockIdx.x * 64;
    const int t = threadIdx.x;
    const int lr = t >> 4, lc = (t & 15) * 4;
#pragma unroll
    for (int i = 0; i < 4; ++i) {
        float4 v = *(const float4*)(src + zb + (size_t)(r0 + lr + i * 16) * C + c0 + lc);
        tile[lr + i * 16][lc + 0] = v.x; tile[lr + i * 16][lc + 1] = v.y;
        tile[lr + i * 16][lc + 2] = v.z; tile[lr + i * 16][lc + 3] = v.w;
    }
    __syncthreads();
#pragma unroll
    for (int i = 0; i < 4; ++i) {
        int cr = lr + i * 16;
        bf16 o[4];
#pragma unroll
        for (int j = 0; j < 4; ++j) o[j] = (bf16)tile[lc + j][cr];
        *(uint2*)(dst + zb + (size_t)(c0 + cr) * R + r0 + lc) = *(uint2*)o;
    }
}

// ---------------------------------------------------------------------------
// fp32 GEMM, 32x256 block, BK=16, 4 waves x 8 wave-uniform rows, lane = 4 cols.
// A read via scalar loads (uniform base via readfirstlane -> SMEM pipe),
// B staged via glds16 + 1 ds_read_b128/kk. Zero LDS bank conflicts (measured).
// K slice [kbeg,kend); bias iff addb. Accumulation kk-sequential.
__device__ __forceinline__ void gemm_body_sg(
    const float* __restrict__ A, const float* __restrict__ B,
    const float* __restrict__ bias, float* __restrict__ C,
    int N, int K, int m0, int n0, int kbeg, int kend, bool addb) {
    __shared__ float Bs[16 * 256];   // [k][n] fp32, glds16 target
    const int t = threadIdx.x;
    const int wv = t >> 6, l = t & 63;
    const int wu = __builtin_amdgcn_readfirstlane(wv);   // force uniform
    const float* Ab = A + (size_t)(m0 + wu * 8) * K;     // wave-uniform base
    const float* gB = B + (size_t)(kbeg + wv * 4) * N + n0 + l * 4;
    float* dB = Bs + (wv * 4) * 256 + l * 4;
    float acc[8][4] = {};
    for (int k0 = kbeg; k0 < kend; k0 += 16) {
        glds16(gB, dB);
        glds16(gB + (size_t)N, dB + 256);
        glds16(gB + (size_t)2 * N, dB + 512);
        glds16(gB + (size_t)3 * N, dB + 768);
        __syncthreads();
#pragma unroll
        for (int q = 0; q < 4; ++q) {
            float4 a4[8];
#pragma unroll
            for (int r = 0; r < 8; ++r)
                a4[r] = *(const float4*)(Ab + (size_t)r * K + k0 + q * 4);
#pragma unroll
            for (int kq = 0; kq < 4; ++kq) {
                float4 b = *(const float4*)&Bs[(q * 4 + kq) * 256 + l * 4];
#pragma unroll
                for (int r = 0; r < 8; ++r) {
                    float av = (kq == 0) ? a4[r].x : (kq == 1) ? a4[r].y
                             : (kq == 2) ? a4[r].z : a4[r].w;
                    acc[r][0] += av * b.x;
                    acc[r][1] += av * b.y;
                    acc[r][2] += av * b.z;
                    acc[r][3] += av * b.w;
                }
            }
        }
        __syncthreads();
        gB += (size_t)16 * N;
    }
#pragma unroll
    for (int r = 0; r < 8; ++r) {
        int m = m0 + wu * 8 + r;
        float4 o;
        o.x = acc[r][0]; o.y = acc[r][1]; o.z = acc[r][2]; o.w = acc[r][3];
        if (addb) {
            o.x += bias[n0 + l * 4 + 0];
            o.y += bias[n0 + l * 4 + 1];
            o.z += bias[n0 + l * 4 + 2];
            o.w += bias[n0 + l * 4 + 3];
        }
        *(float4*)(C + (size_t)m * N + n0 + l * 4) = o;
    }
}

// QKV: grid (3,128,6) flat 2304 = 8 XCD chunks x (16 m-tiles x 3 n x 6 pz).
// pz = proj*2 + ks (ksplit2). m-tile fastest within chunk.
__global__ __launch_bounds__(256) void gemm_qkv_kernel(
    const float* __restrict__ A,
    const float* __restrict__ Wq, const float* __restrict__ Wk,
    const float* __restrict__ Wv,
    const float* __restrict__ bq, const float* __restrict__ bk,
    const float* __restrict__ bv,
    float* __restrict__ q0, float* __restrict__ k0, float* __restrict__ v0,
    float* __restrict__ q1, float* __restrict__ k1, float* __restrict__ v1) {
    const int f = blockIdx.x + 3 * blockIdx.y + 384 * blockIdx.z;  // 0..2303
    const int xcd = f & 7, p = f >> 3;       // p: 0..287
    const int yl = p & 15;                   // m-tile within chunk (fastest)
    const int n  = (p >> 4) % 3;             // n-tile (256 cols)
    const int pz = p / 48;                   // 0..5 = proj*2 + ks
    const int y  = xcd * 16 + yl;            // 0..127
    const int proj = pz >> 1, ks = pz & 1;
    const float* B = (proj == 0) ? Wq : (proj == 1) ? Wk : Wv;
    const float* bias = (proj == 0) ? bq : (proj == 1) ? bk : bv;
    float* C = (proj == 0) ? (ks ? q1 : q0)
             : (proj == 1) ? (ks ? k1 : k0)
                           : (ks ? v1 : v0);
    gemm_body_sg(A, B, bias, C, cH, cH, y * 32, n * 256,
                 ks * 384, ks * 384 + 384, ks == 0);
}

// q += q1; k += k1; v += v1.  q,k,v contiguous (3*TH); q1(tmp),k1(ctx)
// contiguous (2*TH); v1 = d_out scratch.
__global__ __launch_bounds__(256) void reduce_qkv_kernel(
    float* __restrict__ dst2, const float* __restrict__ src2,
    float* __restrict__ v0, const float* __restrict__ v1) {
    const size_t n2 = 2 * TH / 4, n3 = 3 * TH / 4;
    for (size_t i = (size_t)blockIdx.x * 256 + threadIdx.x; i < n3;
         i += (size_t)gridDim.x * 256) {
        if (i < n2) {
            float4 a = ((const float4*)dst2)[i];
            float4 b = ((const float4*)src2)[i];
            a.x += b.x; a.y += b.y; a.z += b.z; a.w += b.w;
            ((float4*)dst2)[i] = a;
        } else {
            size_t j = i - n2;
            float4 a = ((const float4*)v0)[j];
            float4 b = ((const float4*)v1)[j];
            a.x += b.x; a.y += b.y; a.z += b.z; a.w += b.w;
            ((float4*)v0)[j] = a;
        }
    }
}

// Wo: grid (3,128,4) flat 1536, ksplit=4 into dead partial buffers;
// ln_router sums. Same XCD chunk-swizzle.
__global__ __launch_bounds__(256) void gemm_wo_kernel(
    const float* __restrict__ A, const float* __restrict__ W,
    const float* __restrict__ bias,
    float* __restrict__ p0, float* __restrict__ p1,
    float* __restrict__ p2, float* __restrict__ p3) {
    const int f = blockIdx.x + 3 * blockIdx.y + 384 * blockIdx.z;  // 0..1535
    const int xcd = f & 7, p = f >> 3;       // p: 0..191
    const int yl = p & 15;
    const int n  = (p >> 4) % 3;
    const int ks = p / 48;                   // 0..3
    const int y  = xcd * 16 + yl;
    float* C = (ks == 0) ? p0 : (ks == 1) ? p1 : (ks == 2) ? p2 : p3;
    gemm_body_sg(A, W, bias, C, cH, cH, y * 32, n * 256,
                 ks * 192, ks * 192 + 192, ks == 0);
}

// ---------------------------------------------------------------------------
// Flash-style fp32 attention (round-4/8 proven, plain mapping).
__global__ __launch_bounds__(256) void attn_kernel(
    const float* __restrict__ q, const float* __restrict__ k,
    const float* __restrict__ v, float* __restrict__ ctx) {
    __shared__ float sQ[64][68];
    __shared__ float sKV[64][68];
    __shared__ float sS[64][68];
    __shared__ float sM[64], sL[64], sAl[64];
    const int q0 = blockIdx.x * 64, h = blockIdx.y, b = blockIdx.z;
    const int t = threadIdx.x;
    const int lr = t >> 2, lq = (t & 3) * 16;
    {
        const float* gq = q + (size_t)(b * cS + q0 + lr) * cH + h * cDH + lq;
#pragma unroll
        for (int j = 0; j < 4; ++j) {
            float4 x = *(const float4*)(gq + j * 4);
            x.x *= 0.125f; x.y *= 0.125f; x.z *= 0.125f; x.w *= 0.125f;
            *(float4*)&sQ[lr][lq + j * 4] = x;
        }
    }
    if (t < 64) { sM[t] = -1e30f; sL[t] = 0.f; }
    const int c0 = t & 15, rr = (t >> 4) * 4;
    const int d4 = (t & 15) * 4, rp = (t >> 4) * 4;
    const int sr = t >> 2, sc = (t & 3) * 16;
    float4 o_acc[4];
#pragma unroll
    for (int i = 0; i < 4; ++i) o_acc[i] = make_float4(0.f, 0.f, 0.f, 0.f);

    for (int kt = 0; kt < 8; ++kt) {
        float4 kreg[4];
        {
            const float* gk = k + (size_t)(b * cS + kt * 64 + lr) * cH + h * cDH + lq;
#pragma unroll
            for (int j = 0; j < 4; ++j) kreg[j] = *(const float4*)(gk + j * 4);
        }
        __syncthreads();
#pragma unroll
        for (int j = 0; j < 4; ++j) *(float4*)&sKV[lr][lq + j * 4] = kreg[j];
        __syncthreads();
        float accS[4][4] = {};
#pragma unroll
        for (int d = 0; d < 64; d += 4) {
            float4 qv[4], kv[4];
#pragma unroll
            for (int i = 0; i < 4; ++i) qv[i] = *(const float4*)&sQ[rr + i][d];
#pragma unroll
            for (int j = 0; j < 4; ++j) kv[j] = *(const float4*)&sKV[c0 + 16 * j][d];
#pragma unroll
            for (int i = 0; i < 4; ++i)
#pragma unroll
                for (int j = 0; j < 4; ++j)
                    accS[i][j] += qv[i].x * kv[j].x + qv[i].y * kv[j].y +
                                  qv[i].z * kv[j].z + qv[i].w * kv[j].w;
        }
#pragma unroll
        for (int i = 0; i < 4; ++i)
#pragma unroll
            for (int j = 0; j < 4; ++j) sS[rr + i][c0 + 16 * j] = accS[i][j];
        float4 vreg[4];
        {
            const float* gv = v + (size_t)(b * cS + kt * 64 + lr) * cH + h * cDH + lq;
#pragma unroll
            for (int j = 0; j < 4; ++j) vreg[j] = *(const float4*)(gv + j * 4);
        }
        __syncthreads();
        {
            float4 s[4];
#pragma unroll
            for (int j = 0; j < 4; ++j) s[j] = *(const float4*)&sS[sr][sc + j * 4];
            float m = -1e30f;
#pragma unroll
            for (int j = 0; j < 4; ++j)
                m = fmaxf(m, fmaxf(fmaxf(s[j].x, s[j].y), fmaxf(s[j].z, s[j].w)));
            m = fmaxf(m, __shfl_xor(m, 1));
            m = fmaxf(m, __shfl_xor(m, 2));
            float m_old = sM[sr];
            float m_new = fmaxf(m_old, m);
            float sum = 0.f;
#pragma unroll
            for (int j = 0; j < 4; ++j) {
                s[j].x = __expf(s[j].x - m_new); s[j].y = __expf(s[j].y - m_new);
                s[j].z = __expf(s[j].z - m_new); s[j].w = __expf(s[j].w - m_new);
                sum += s[j].x + s[j].y + s[j].z + s[j].w;
                *(float4*)&sS[sr][sc + j * 4] = s[j];
            }
            sum += __shfl_xor(sum, 1);
            sum += __shfl_xor(sum, 2);
            if ((t & 3) == 0) {
                float alpha = __expf(m_old - m_new);
                sAl[sr] = alpha;
                sM[sr] = m_new;
                sL[sr] = sL[sr] * alpha + sum;
            }
        }
#pragma unroll
        for (int j = 0; j < 4; ++j) *(float4*)&sKV[lr][lq + j * 4] = vreg[j];
        __syncthreads();
#pragma unroll
        for (int i = 0; i < 4; ++i) {
            float al = sAl[rp + i];
            o_acc[i].x *= al; o_acc[i].y *= al; o_acc[i].z *= al; o_acc[i].w *= al;
        }
        for (int kk4 = 0; kk4 < 64; kk4 += 4) {
            float4 pv[4], vv[4];
#pragma unroll
            for (int i = 0; i < 4; ++i) pv[i] = *(const float4*)&sS[rp + i][kk4];
#pragma unroll
            for (int j = 0; j < 4; ++j) vv[j] = *(const float4*)&sKV[kk4 + j][d4];
#pragma unroll
            for (int i = 0; i < 4; ++i) {
                o_acc[i].x += pv[i].x * vv[0].x + pv[i].y * vv[1].x +
                              pv[i].z * vv[2].x + pv[i].w * vv[3].x;
                o_acc[i].y += pv[i].x * vv[0].y + pv[i].y * vv[1].y +
                              pv[i].z * vv[2].y + pv[i].w * vv[3].y;
                o_acc[i].z += pv[i].x * vv[0].z + pv[i].y * vv[1].z +
                              pv[i].z * vv[2].z + pv[i].w * vv[3].z;
                o_acc[i].w += pv[i].x * vv[0].w + pv[i].y * vv[1].w +
                              pv[i].z * vv[2].w + pv[i].w * vv[3].w;
            }
        }
    }
    __syncthreads();
#pragma unroll
    for (int i = 0; i < 4; ++i) {
        float inv = 1.0f / sL[rp + i];
        float4 o = o_acc[i];
        o.x *= inv; o.y *= inv; o.z *= inv; o.w *= inv;
        *(float4*)(ctx + (size_t)(b * cS + q0 + rp + i) * cH + h * cDH + d4) = o;
    }
}

__device__ __forceinline__ float block_reduce_sum(float v, float* red) {
#pragma unroll
    for (int o = 32; o; o >>= 1) v += __shfl_xor(v, o);
    __syncthreads();
    if ((threadIdx.x & 63) == 0) red[threadIdx.x >> 6] = v;
    __syncthreads();
    return red[0] + red[1] + red[2] + red[3];
}

// ---------------------------------------------------------------------------
// LN1 + LN2 + router, fp32 (selection-exact). Dense = four K-split partials.
__global__ __launch_bounds__(256) void ln_router_kernel(
    const float* __restrict__ dense0, const float* __restrict__ dense1,
    const float* __restrict__ dense2, const float* __restrict__ dense3,
    const float* __restrict__ resid,
    const float* __restrict__ g1, const float* __restrict__ b1,
    const float* __restrict__ g2, const float* __restrict__ b2,
    const float* __restrict__ Wr, const float* __restrict__ br,
    float* __restrict__ out, bf16* __restrict__ xlb,
    float* __restrict__ out_logits, float* __restrict__ wgt,
    int* __restrict__ counts, int* __restrict__ lists) {
    __shared__ float red[4];
    __shared__ float lred[4][8];
    const int t = blockIdx.x, tid = threadIdx.x;
    const size_t base = (size_t)t * cH;
    float v[3], s = 0.f;
#pragma unroll
    for (int i = 0; i < 3; ++i) {
        size_t ix = base + tid + 256 * i;
        v[i] = dense0[ix] + dense1[ix] + dense2[ix] + dense3[ix] + resid[ix];
        s += v[i];
    }
    const float mean = block_reduce_sum(s, red) * (1.0f / cH);
    float vs = 0.f;
#pragma unroll
    for (int i = 0; i < 3; ++i) { float d = v[i] - mean; vs += d * d; }
    const float rstd = rsqrtf(block_reduce_sum(vs, red) * (1.0f / cH) + 1e-12f);
    float a[3], s2 = 0.f;
#pragma unroll
    for (int i = 0; i < 3; ++i) {
        a[i] = (v[i] - mean) * rstd * g1[tid + 256 * i] + b1[tid + 256 * i];
        out[base + tid + 256 * i] = a[i];
        s2 += a[i];
    }
    const float mean2 = block_reduce_sum(s2, red) * (1.0f / cH);
    float vs2 = 0.f;
#pragma unroll
    for (int i = 0; i < 3; ++i) { float d = a[i] - mean2; vs2 += d * d; }
    const float rstd2 = rsqrtf(block_reduce_sum(vs2, red) * (1.0f / cH) + 1e-12f);
    float xl[3];
#pragma unroll
    for (int i = 0; i < 3; ++i) {
        xl[i] = (a[i] - mean2) * rstd2 * g2[tid + 256 * i] + b2[tid + 256 * i];
        xlb[base + tid + 256 * i] = (bf16)xl[i];
    }
    float lg[cE] = {};
#pragma unroll
    for (int i = 0; i < 3; ++i) {
        const float* wr = Wr + (size_t)(tid + 256 * i) * cE;
#pragma unroll
        for (int e = 0; e < cE; ++e) lg[e] += xl[i] * wr[e];
    }
#pragma unroll
    for (int e = 0; e < cE; ++e)
#pragma unroll
        for (int o = 32; o; o >>= 1) lg[e] += __shfl_xor(lg[e], o);
    if ((tid & 63) == 0)
#pragma unroll
        for (int e = 0; e < cE; ++e) lred[tid >> 6][e] = lg[e];
    __syncthreads();
    if (tid == 0) {
        float logits[cE];
#pragma unroll
        for (int e = 0; e < cE; ++e) {
            logits[e] = lred[0][e] + lred[1][e] + lred[2][e] + lred[3][e] + br[e];
            out_logits[(size_t)t * cE + e] = logits[e];
        }
        int i0 = 0;
        for (int e = 1; e < cE; ++e) if (logits[e] > logits[i0]) i0 = e;
        int i1 = (i0 == 0) ? 1 : 0;
        for (int e = 0; e < cE; ++e)
            if (e != i0 && logits[e] > logits[i1]) i1 = e;
        float e1 = __expf(logits[i1] - logits[i0]);
        float w0 = 1.0f / (1.0f + e1);
        float w1 = e1 * w0;
        wgt[t * 2 + 0] = w0;
        wgt[t * 2 + 1] = w1;
        int p0 = atomicAdd(&counts[i0], 1);
        lists[i0 * cT + p0] = t * 2 + 0;
        int p1 = atomicAdd(&counts[i1], 1);
        lists[i1 * cT + p1] = t * 2 + 1;
    }
}

// ---------------------------------------------------------------------------
// Expert up, 128x64 tile, BK=64 as two [.][32] sub-tiles (round 14).
// Per 64-K-step: 8 glds16, 1 barrier-pair, 2x16 MFMA/wave (was 2 barrier-
// pairs, 2x8... i.e. barriers halved). Fragment geometry identical to BK=32.
__global__ __launch_bounds__(256) void expert_up_mfma_kernel(
    const bf16* __restrict__ xlb,
    const bf16* __restrict__ WupT, const bf16* __restrict__ WnewT,
    const float* __restrict__ b_up, const float* __restrict__ b_new,
    const int* __restrict__ counts, const int* __restrict__ lists,
    bf16* __restrict__ act) {
    const int e = blockIdx.z;
    const int cnt = counts[e];
    const int m0 = blockIdx.y * 128;
    if (m0 >= cnt) return;
    const int n0 = blockIdx.x * 64;
    __shared__ short sA[2 * 128 * 32], sB1[2 * 64 * 32], sB2[2 * 64 * 32];
    __shared__ int rowa[128];
    const int t = threadIdx.x;
    if (t < 128) {
        int idx = m0 + t;
        rowa[t] = (idx < cnt) ? lists[e * cT + idx] : -1;
    }
    __syncthreads();
    const int lane = t & 63, w = t >> 6;
    const int wm = (w >> 1) * 64, wn = (w & 1) * 32;
    const int rA0 = t >> 2, kc8 = (t & 3) * 8;
    int a0 = rowa[rA0], a1 = rowa[rA0 + 64];
    const bf16* gA0 = xlb + (size_t)(a0 < 0 ? 0 : (a0 >> 1)) * cH + kc8;
    const bf16* gA1 = xlb + (size_t)(a1 < 0 ? 0 : (a1 >> 1)) * cH + kc8;
    const bf16* B1 = WupT + (size_t)e * cI * cH;
    const bf16* B2 = WnewT + (size_t)e * cI * cH;
    const bf16* gB1 = B1 + (size_t)(n0 + rA0) * cH + kc8;
    const bf16* gB2 = B2 + (size_t)(n0 + rA0) * cH + kc8;
    // LDS dests: linear thread-order chunks (glds16 wave-uniform-base rule)
    short* dA0 = sA + t * 8;            // ks0, row rA0
    short* dA1 = sA + (t + 256) * 8;    // ks0, row rA0+64
    short* dA2 = sA + (t + 512) * 8;    // ks1, row rA0
    short* dA3 = sA + (t + 768) * 8;    // ks1, row rA0+64
    short* dB1a = sB1 + t * 8;          // ks0
    short* dB1b = sB1 + (t + 256) * 8;  // ks1
    short* dB2a = sB2 + t * 8;
    short* dB2b = sB2 + (t + 256) * 8;
    f4v zero = {0.f, 0.f, 0.f, 0.f};
    f4v acc1[4][2], acc2[4][2];
#pragma unroll
    for (int i = 0; i < 4; ++i)
#pragma unroll
        for (int j = 0; j < 2; ++j) { acc1[i][j] = zero; acc2[i][j] = zero; }
    const int fr = lane & 15, kg = (lane >> 4) * 8;
    for (int kk = 0; kk < cH; kk += 64) {
        glds16(gA0 + kk, dA0);      glds16(gA1 + kk, dA1);
        glds16(gA0 + kk + 32, dA2); glds16(gA1 + kk + 32, dA3);
        glds16(gB1 + kk, dB1a);     glds16(gB1 + kk + 32, dB1b);
        glds16(gB2 + kk, dB2a);     glds16(gB2 + kk + 32, dB2b);
        __syncthreads();
#pragma unroll
        for (int ks = 0; ks < 2; ++ks) {
            const short* pA  = sA  + ks * 4096;
            const short* pB1 = sB1 + ks * 2048;
            const short* pB2 = sB2 + ks * 2048;
            s8v af[4], bf1[2], bf2[2];
#pragma unroll
            for (int i = 0; i < 4; ++i)
                af[i] = *(const s8v*)(pA + (wm + i * 16 + fr) * 32 + kg);
#pragma unroll
            for (int j = 0; j < 2; ++j) {
                bf1[j] = *(const s8v*)(pB1 + (wn + j * 16 + fr) * 32 + kg);
                bf2[j] = *(const s8v*)(pB2 + (wn + j * 16 + fr) * 32 + kg);
            }
#pragma unroll
            for (int mi = 0; mi < 4; ++mi)
#pragma unroll
                for (int ni = 0; ni < 2; ++ni) {
                    acc1[mi][ni] = __builtin_amdgcn_mfma_f32_16x16x32_bf16(
                        af[mi], bf1[ni], acc1[mi][ni], 0, 0, 0);
                    acc2[mi][ni] = __builtin_amdgcn_mfma_f32_16x16x32_bf16(
                        af[mi], bf2[ni], acc2[mi][ni], 0, 0, 0);
                }
        }
        __syncthreads();
    }
    const int cn = lane & 15, rq = (lane >> 4) * 4;
#pragma unroll
    for (int mi = 0; mi < 4; ++mi)
#pragma unroll
        for (int r = 0; r < 4; ++r) {
            int ml = wm + mi * 16 + rq + r;
            int a = rowa[ml];
            if (a < 0) continue;
            bf16* orow = act + (size_t)a * cI + n0 + wn;
#pragma unroll
            for (int ni = 0; ni < 2; ++ni) {
                int nl = ni * 16 + cn;
                float up = acc1[mi][ni][r] + b_up[e * cI + n0 + wn + nl];
                float nw = acc2[mi][ni][r] + b_new[e * cI + n0 + wn + nl];
                float g = 0.5f * up * (1.0f + erff(up * 0.70710678118654752f));
                orow[nl] = (bf16)(g * nw);
            }
        }
}

// Expert down (128x128), BK=64 as two [.][32] sub-tiles (round 14).
__global__ __launch_bounds__(256) void expert_down_mfma_kernel(
    const bf16* __restrict__ act, const bf16* __restrict__ WdownT,
    const float* __restrict__ b_down,
    const int* __restrict__ counts, const int* __restrict__ lists,
    const float* __restrict__ wgt, float* __restrict__ out) {
    const int e = blockIdx.z;
    const int cnt = counts[e];
    const int m0 = blockIdx.y * 128;
    if (m0 >= cnt) return;
    const int n0 = blockIdx.x * 128;
    __shared__ short sA[2 * 128 * 32], sB[2 * 128 * 32];
    __shared__ int rowa[128];
    const int t = threadIdx.x;
    if (t < 128) {
        int idx = m0 + t;
        rowa[t] = (idx < cnt) ? lists[e * cT + idx] : -1;
    }
    __syncthreads();
    const int lane = t & 63, w = t >> 6;
    const int wm = (w >> 1) * 64, wn = (w & 1) * 64;
    const int rA0 = t >> 2, kc8 = (t & 3) * 8;
    int a0 = rowa[rA0], a1 = rowa[rA0 + 64];
    const bf16* gA0 = act + (size_t)(a0 < 0 ? 0 : a0) * cI + kc8;
    const bf16* gA1 = act + (size_t)(a1 < 0 ? 0 : a1) * cI + kc8;
    const bf16* BT = WdownT + (size_t)e * cH * cI;
    const bf16* gB0 = BT + (size_t)(n0 + rA0) * cI + kc8;
    const bf16* gB1 = BT + (size_t)(n0 + rA0 + 64) * cI + kc8;
    short* dA0 = sA + t * 8;            // ks0, row rA0
    short* dA1 = sA + (t + 256) * 8;    // ks0, row rA0+64
    short* dA2 = sA + (t + 512) * 8;    // ks1, row rA0
    short* dA3 = sA + (t + 768) * 8;    // ks1, row rA0+64
    short* dB0 = sB + t * 8;
    short* dB1d = sB + (t + 256) * 8;
    short* dB2 = sB + (t + 512) * 8;
    short* dB3 = sB + (t + 768) * 8;
    f4v zero = {0.f, 0.f, 0.f, 0.f};
    f4v acc[4][4];
#pragma unroll
    for (int i = 0; i < 4; ++i)
#pragma unroll
        for (int j = 0; j < 4; ++j) acc[i][j] = zero;
    const int fr = lane & 15, kg = (lane >> 4) * 8;
    for (int kk = 0; kk < cI; kk += 64) {
        glds16(gA0 + kk, dA0);      glds16(gA1 + kk, dA1);
        glds16(gA0 + kk + 32, dA2); glds16(gA1 + kk + 32, dA3);
        glds16(gB0 + kk, dB0);      glds16(gB1 + kk, dB1d);
        glds16(gB0 + kk + 32, dB2); glds16(gB1 + kk + 32, dB3);
        __syncthreads();
#pragma unroll
        for (int ks = 0; ks < 2; ++ks) {
            const short* pA = sA + ks * 4096;
            const short* pB = sB + ks * 4096;
            s8v af[4], bf[4];
#pragma unroll
            for (int i = 0; i < 4; ++i)
                af[i] = *(const s8v*)(pA + (wm + i * 16 + fr) * 32 + kg);
#pragma unroll
            for (int i = 0; i < 4; ++i)
                bf[i] = *(const s8v*)(pB + (wn + i * 16 + fr) * 32 + kg);
#pragma unroll
            for (int mi = 0; mi < 4; ++mi)
#pragma unroll
                for (int ni = 0; ni < 4; ++ni)
                    acc[mi][ni] = __builtin_amdgcn_mfma_f32_16x16x32_bf16(
                        af[mi], bf[ni], acc[mi][ni], 0, 0, 0);
        }
        __syncthreads();
    }
    const int cn = lane & 15, rq = (lane >> 4) * 4;
#pragma unroll
    for (int mi = 0; mi < 4; ++mi)
#pragma unroll
        for (int r = 0; r < 4; ++r) {
            int ml = wm + mi * 16 + rq + r;
            int a = rowa[ml];
            if (a < 0) continue;
            int token = a >> 1;
            float wv = wgt[a];
#pragma unroll
            for (int ni = 0; ni < 4; ++ni) {
                int n = n0 + wn + ni * 16 + cn;
                atomicAdd(&out[(size_t)token * cH + n],
                          wv * (acc[mi][ni][r] + b_down[e * cH + n]));
            }
        }
}

// ---------------------------------------------------------------------------
extern "C" void kernel_launch(void* const* d_in, const int* in_sizes, int n_in,
                              void* d_out, int out_size, void* d_ws, size_t ws_size,
                              hipStream_t stream) {
    const float* x      = (const float*)d_in[0];
    const float* Wq     = (const float*)d_in[1];
    const float* bq     = (const float*)d_in[2];
    const float* Wk     = (const float*)d_in[3];
    const float* bk     = (const float*)d_in[4];
    const float* Wv     = (const float*)d_in[5];
    const float* bv     = (const float*)d_in[6];
    const float* Wo     = (const float*)d_in[7];
    const float* bo     = (const float*)d_in[8];
    const float* ln1g   = (const float*)d_in[9];
    const float* ln1b   = (const float*)d_in[10];
    const float* ln2g   = (const float*)d_in[11];
    const float* ln2b   = (const float*)d_in[12];
    const float* Wr     = (const float*)d_in[13];
    const float* br     = (const float*)d_in[14];
    const float* W_up   = (const float*)d_in[15];
    const float* b_up   = (const float*)d_in[16];
    const float* W_new  = (const float*)d_in[17];
    const float* b_new  = (const float*)d_in[18];
    const float* W_down = (const float*)d_in[19];
    const float* b_down = (const float*)d_in[20];

    float* out = (float*)d_out;
    float* ws  = (float*)d_ws;

    bf16* WupT   = (bf16*)(ws + OFF_WUP_T);
    bf16* WnewT  = (bf16*)(ws + OFF_WNEW_T);
    bf16* WdownT = (bf16*)(ws + OFF_WDOWN_T);
    float* q     = ws + OFF_QKV;
    float* k     = ws + OFF_QKV + TH;
    float* v     = ws + OFF_QKV + 2 * TH;
    float* tmp   = ws + OFF_QKV + 3 * TH;
    bf16* act    = (bf16*)(ws + OFF_QKV);   // aliases q/k/v/tmp (dead by then)
    float* ctx   = ws + OFF_CTX;
    bf16* xlb    = (bf16*)(ws + OFF_XLB);
    float* wgt   = ws + OFF_WGT;
    int* counts  = (int*)(ws + OFF_COUNTS);
    int* lists   = (int*)(ws + OFF_LISTS);

    init_counts_kernel<<<1, 64, 0, stream>>>(counts);

    // expert weight transpose+convert
    transpose_bf16_kernel<<<dim3(48, 12, cE), 256, 0, stream>>>(W_up, WupT, cH, cI);
    transpose_bf16_kernel<<<dim3(48, 12, cE), 256, 0, stream>>>(W_new, WnewT, cH, cI);
    transpose_bf16_kernel<<<dim3(12, 48, cE), 256, 0, stream>>>(W_down, WdownT, cI, cH);

    // fp32 pre-router path (selection-exact), round-11 config:
    // 32x256 s_load body + QKV ksplit2 (partials q1->tmp, k1->ctx, v1->out).
    gemm_qkv_kernel<<<dim3(3, 128, 6), 256, 0, stream>>>(
        x, Wq, Wk, Wv, bq, bk, bv, q, k, v, tmp, ctx, out);
    reduce_qkv_kernel<<<2048, 256, 0, stream>>>(q, tmp, v, out);
    attn_kernel<<<dim3(cS / 64, cNH, cB), 256, 0, stream>>>(q, k, v, ctx);
    // Wo ksplit=4: partials into dead q,k,v,tmp; summed inside ln_router
    gemm_wo_kernel<<<dim3(3, 128, 4), 256, 0, stream>>>(
        ctx, Wo, bo, q, k, v, tmp);
    ln_router_kernel<<<cT, 256, 0, stream>>>(
        q, k, v, tmp, x, ln1g, ln1b, ln2g, ln2b, Wr, br,
        out, xlb, out + TH, wgt, counts, lists);

    // bf16 MFMA experts (scatter-add into out), BK=64
    expert_up_mfma_kernel<<<dim3(cI / 64, cT / 128, cE), 256, 0, stream>>>(
        xlb, WupT, WnewT, b_up, b_new, counts, lists, act);
    expert_down_mfma_kernel<<<dim3(cH / 128, cT / 128, cE), 256, 0, stream>>>(
        act, WdownT, b_down, counts, lists, wgt, out);
}

// Round 10
// 1023.761 us; speedup vs baseline: 1.1401x; 1.0011x over previous
//
#include <hip/hip_runtime.h>
#include <hip/hip_bf16.h>
#include <cmath>

// ---------------------------------------------------------------------------
// BertLayer + top-2 MoE, MI355X. Round 15:
//  - Experts: LDS DOUBLE-BUFFER (T3 2-phase template). stage(t+1) is issued
//    into buf^1 BEFORE compute(t), so the vmcnt(0) drain at the barrier has
//    the whole compute phase in flight (was: stage -> barrier-drain with zero
//    overlap -> ~55% stall). glds16-only staging => no VGPR cost (round-6
//    failure mode avoided). LDS 32.5 -> 64.5KB (2 blk/CU; port-bound kernel,
//    8 waves still saturate). Compute order per element unchanged: bit-exact.
//  - Everything else byte-identical to round 14 (best, 1024.9us):
//    fp32 32x256 s_load body + QKV ksplit2 + reduce_qkv + Wo ksplit4,
//    round-8 attn, BK=64 expert tiling.
// ---------------------------------------------------------------------------

constexpr int cB = 8, cS = 512, cH = 768, cNH = 12, cDH = 64, cI = 3072, cE = 8;
constexpr int cT = cB * cS;                       // 4096 tokens
constexpr size_t TH = (size_t)cT * cH;            // 3,145,728

typedef __hip_bfloat16 bf16;
typedef __attribute__((ext_vector_type(8))) short s8v;   // 8 bf16 = 4 VGPRs
typedef __attribute__((ext_vector_type(4))) float f4v;   // MFMA accumulator

// ---- workspace layout (float units) ---------------------------------------
constexpr size_t SZ_WEXP     = (size_t)cE * cI * cH / 2;        // 9,437,184
constexpr size_t OFF_WUP_T   = 0;                               // [E][I][H] bf16
constexpr size_t OFF_WNEW_T  = OFF_WUP_T + SZ_WEXP;
constexpr size_t OFF_WDOWN_T = OFF_WNEW_T + SZ_WEXP;            // [E][H][I] bf16
constexpr size_t OFF_QKV     = OFF_WDOWN_T + SZ_WEXP;           // q,k,v,tmp fp32
constexpr size_t OFF_CTX     = OFF_QKV + 4 * TH;                // ctx fp32
constexpr size_t OFF_XLB     = OFF_CTX + TH;                    // xl bf16
constexpr size_t OFF_WGT     = OFF_XLB + TH / 2;                // 2T fp32
constexpr size_t OFF_COUNTS  = OFF_WGT + 2 * cT;                // int[16]
constexpr size_t OFF_LISTS   = OFF_COUNTS + 16;                 // int[E*T]
// act (bf16) aliases q/k/v/tmp region (dead once ln_router consumed partials).
// d_out is used as v1 K-split scratch before ln_router rewrites it fully.

// ---------------------------------------------------------------------------
__device__ __forceinline__ void glds16(const void* g, void* l) {
    __builtin_amdgcn_global_load_lds(
        (const __attribute__((address_space(1))) unsigned int*)g,
        (__attribute__((address_space(3))) unsigned int*)l, 16, 0, 0);
}

__global__ void init_counts_kernel(int* __restrict__ counts) {
    if (threadIdx.x < cE) counts[threadIdx.x] = 0;
}

// src [z][R][C] fp32 -> dst [z][C][R] bf16   (R,C multiples of 64)
__global__ __launch_bounds__(256) void transpose_bf16_kernel(
    const float* __restrict__ src, bf16* __restrict__ dst, int R, int C) {
    __shared__ float tile[64][65];
    const size_t zb = (size_t)blockIdx.z * R * C;
    const int r0 = blockIdx.y * 64, c0 = blockIdx.x * 64;
    const int t = threadIdx.x;
    const int lr = t >> 4, lc = (t & 15) * 4;
#pragma unroll
    for (int i = 0; i < 4; ++i) {
        float4 v = *(const float4*)(src + zb + (size_t)(r0 + lr + i * 16) * C + c0 + lc);
        tile[lr + i * 16][lc + 0] = v.x; tile[lr + i * 16][lc + 1] = v.y;
        tile[lr + i * 16][lc + 2] = v.z; tile[lr + i * 16][lc + 3] = v.w;
    }
    __syncthreads();
#pragma unroll
    for (int i = 0; i < 4; ++i) {
        int cr = lr + i * 16;
        bf16 o[4];
#pragma unroll
        for (int j = 0; j < 4; ++j) o[j] = (bf16)tile[lc + j][cr];
        *(uint2*)(dst + zb + (size_t)(c0 + cr) * R + r0 + lc) = *(uint2*)o;
    }
}

// ---------------------------------------------------------------------------
// fp32 GEMM, 32x256 block, BK=16, 4 waves x 8 wave-uniform rows, lane = 4 cols.
// A read via scalar loads (uniform base via readfirstlane -> SMEM pipe),
// B staged via glds16 + 1 ds_read_b128/kk. Zero LDS bank conflicts (measured).
// K slice [kbeg,kend); bias iff addb. Accumulation kk-sequential.
__device__ __forceinline__ void gemm_body_sg(
    const float* __restrict__ A, const float* __restrict__ B,
    const float* __restrict__ bias, float* __restrict__ C,
    int N, int K, int m0, int n0, int kbeg, int kend, bool addb) {
    __shared__ float Bs[16 * 256];   // [k][n] fp32, glds16 target
    const int t = threadIdx.x;
    const int wv = t >> 6, l = t & 63;
    const int wu = __builtin_amdgcn_readfirstlane(wv);   // force uniform
    const float* Ab = A + (size_t)(m0 + wu * 8) * K;     // wave-uniform base
    const float* gB = B + (size_t)(kbeg + wv * 4) * N + n0 + l * 4;
    float* dB = Bs + (wv * 4) * 256 + l * 4;
    float acc[8][4] = {};
    for (int k0 = kbeg; k0 < kend; k0 += 16) {
        glds16(gB, dB);
        glds16(gB + (size_t)N, dB + 256);
        glds16(gB + (size_t)2 * N, dB + 512);
        glds16(gB + (size_t)3 * N, dB + 768);
        __syncthreads();
#pragma unroll
        for (int q = 0; q < 4; ++q) {
            float4 a4[8];
#pragma unroll
            for (int r = 0; r < 8; ++r)
                a4[r] = *(const float4*)(Ab + (size_t)r * K + k0 + q * 4);
#pragma unroll
            for (int kq = 0; kq < 4; ++kq) {
                float4 b = *(const float4*)&Bs[(q * 4 + kq) * 256 + l * 4];
#pragma unroll
                for (int r = 0; r < 8; ++r) {
                    float av = (kq == 0) ? a4[r].x : (kq == 1) ? a4[r].y
                             : (kq == 2) ? a4[r].z : a4[r].w;
                    acc[r][0] += av * b.x;
                    acc[r][1] += av * b.y;
                    acc[r][2] += av * b.z;
                    acc[r][3] += av * b.w;
                }
            }
        }
        __syncthreads();
        gB += (size_t)16 * N;
    }
#pragma unroll
    for (int r = 0; r < 8; ++r) {
        int m = m0 + wu * 8 + r;
        float4 o;
        o.x = acc[r][0]; o.y = acc[r][1]; o.z = acc[r][2]; o.w = acc[r][3];
        if (addb) {
            o.x += bias[n0 + l * 4 + 0];
            o.y += bias[n0 + l * 4 + 1];
            o.z += bias[n0 + l * 4 + 2];
            o.w += bias[n0 + l * 4 + 3];
        }
        *(float4*)(C + (size_t)m * N + n0 + l * 4) = o;
    }
}

// QKV: grid (3,128,6) flat 2304 = 8 XCD chunks x (16 m-tiles x 3 n x 6 pz).
// pz = proj*2 + ks (ksplit2). m-tile fastest within chunk.
__global__ __launch_bounds__(256) void gemm_qkv_kernel(
    const float* __restrict__ A,
    const float* __restrict__ Wq, const float* __restrict__ Wk,
    const float* __restrict__ Wv,
    const float* __restrict__ bq, const float* __restrict__ bk,
    const float* __restrict__ bv,
    float* __restrict__ q0, float* __restrict__ k0, float* __restrict__ v0,
    float* __restrict__ q1, float* __restrict__ k1, float* __restrict__ v1) {
    const int f = blockIdx.x + 3 * blockIdx.y + 384 * blockIdx.z;  // 0..2303
    const int xcd = f & 7, p = f >> 3;       // p: 0..287
    const int yl = p & 15;                   // m-tile within chunk (fastest)
    const int n  = (p >> 4) % 3;             // n-tile (256 cols)
    const int pz = p / 48;                   // 0..5 = proj*2 + ks
    const int y  = xcd * 16 + yl;            // 0..127
    const int proj = pz >> 1, ks = pz & 1;
    const float* B = (proj == 0) ? Wq : (proj == 1) ? Wk : Wv;
    const float* bias = (proj == 0) ? bq : (proj == 1) ? bk : bv;
    float* C = (proj == 0) ? (ks ? q1 : q0)
             : (proj == 1) ? (ks ? k1 : k0)
                           : (ks ? v1 : v0);
    gemm_body_sg(A, B, bias, C, cH, cH, y * 32, n * 256,
                 ks * 384, ks * 384 + 384, ks == 0);
}

// q += q1; k += k1; v += v1.  q,k,v contiguous (3*TH); q1(tmp),k1(ctx)
// contiguous (2*TH); v1 = d_out scratch.
__global__ __launch_bounds__(256) void reduce_qkv_kernel(
    float* __restrict__ dst2, const float* __restrict__ src2,
    float* __restrict__ v0, const float* __restrict__ v1) {
    const size_t n2 = 2 * TH / 4, n3 = 3 * TH / 4;
    for (size_t i = (size_t)blockIdx.x * 256 + threadIdx.x; i < n3;
         i += (size_t)gridDim.x * 256) {
        if (i < n2) {
            float4 a = ((const float4*)dst2)[i];
            float4 b = ((const float4*)src2)[i];
            a.x += b.x; a.y += b.y; a.z += b.z; a.w += b.w;
            ((float4*)dst2)[i] = a;
        } else {
            size_t j = i - n2;
            float4 a = ((const float4*)v0)[j];
            float4 b = ((const float4*)v1)[j];
            a.x += b.x; a.y += b.y; a.z += b.z; a.w += b.w;
            ((float4*)v0)[j] = a;
        }
    }
}

// Wo: grid (3,128,4) flat 1536, ksplit=4 into dead partial buffers;
// ln_router sums. Same XCD chunk-swizzle.
__global__ __launch_bounds__(256) void gemm_wo_kernel(
    const float* __restrict__ A, const float* __restrict__ W,
    const float* __restrict__ bias,
    float* __restrict__ p0, float* __restrict__ p1,
    float* __restrict__ p2, float* __restrict__ p3) {
    const int f = blockIdx.x + 3 * blockIdx.y + 384 * blockIdx.z;  // 0..1535
    const int xcd = f & 7, p = f >> 3;       // p: 0..191
    const int yl = p & 15;
    const int n  = (p >> 4) % 3;
    const int ks = p / 48;                   // 0..3
    const int y  = xcd * 16 + yl;
    float* C = (ks == 0) ? p0 : (ks == 1) ? p1 : (ks == 2) ? p2 : p3;
    gemm_body_sg(A, W, bias, C, cH, cH, y * 32, n * 256,
                 ks * 192, ks * 192 + 192, ks == 0);
}

// ---------------------------------------------------------------------------
// Flash-style fp32 attention (round-4/8 proven, plain mapping).
__global__ __launch_bounds__(256) void attn_kernel(
    const float* __restrict__ q, const float* __restrict__ k,
    const float* __restrict__ v, float* __restrict__ ctx) {
    __shared__ float sQ[64][68];
    __shared__ float sKV[64][68];
    __shared__ float sS[64][68];
    __shared__ float sM[64], sL[64], sAl[64];
    const int q0 = blockIdx.x * 64, h = blockIdx.y, b = blockIdx.z;
    const int t = threadIdx.x;
    const int lr = t >> 2, lq = (t & 3) * 16;
    {
        const float* gq = q + (size_t)(b * cS + q0 + lr) * cH + h * cDH + lq;
#pragma unroll
        for (int j = 0; j < 4; ++j) {
            float4 x = *(const float4*)(gq + j * 4);
            x.x *= 0.125f; x.y *= 0.125f; x.z *= 0.125f; x.w *= 0.125f;
            *(float4*)&sQ[lr][lq + j * 4] = x;
        }
    }
    if (t < 64) { sM[t] = -1e30f; sL[t] = 0.f; }
    const int c0 = t & 15, rr = (t >> 4) * 4;
    const int d4 = (t & 15) * 4, rp = (t >> 4) * 4;
    const int sr = t >> 2, sc = (t & 3) * 16;
    float4 o_acc[4];
#pragma unroll
    for (int i = 0; i < 4; ++i) o_acc[i] = make_float4(0.f, 0.f, 0.f, 0.f);

    for (int kt = 0; kt < 8; ++kt) {
        float4 kreg[4];
        {
            const float* gk = k + (size_t)(b * cS + kt * 64 + lr) * cH + h * cDH + lq;
#pragma unroll
            for (int j = 0; j < 4; ++j) kreg[j] = *(const float4*)(gk + j * 4);
        }
        __syncthreads();
#pragma unroll
        for (int j = 0; j < 4; ++j) *(float4*)&sKV[lr][lq + j * 4] = kreg[j];
        __syncthreads();
        float accS[4][4] = {};
#pragma unroll
        for (int d = 0; d < 64; d += 4) {
            float4 qv[4], kv[4];
#pragma unroll
            for (int i = 0; i < 4; ++i) qv[i] = *(const float4*)&sQ[rr + i][d];
#pragma unroll
            for (int j = 0; j < 4; ++j) kv[j] = *(const float4*)&sKV[c0 + 16 * j][d];
#pragma unroll
            for (int i = 0; i < 4; ++i)
#pragma unroll
                for (int j = 0; j < 4; ++j)
                    accS[i][j] += qv[i].x * kv[j].x + qv[i].y * kv[j].y +
                                  qv[i].z * kv[j].z + qv[i].w * kv[j].w;
        }
#pragma unroll
        for (int i = 0; i < 4; ++i)
#pragma unroll
            for (int j = 0; j < 4; ++j) sS[rr + i][c0 + 16 * j] = accS[i][j];
        float4 vreg[4];
        {
            const float* gv = v + (size_t)(b * cS + kt * 64 + lr) * cH + h * cDH + lq;
#pragma unroll
            for (int j = 0; j < 4; ++j) vreg[j] = *(const float4*)(gv + j * 4);
        }
        __syncthreads();
        {
            float4 s[4];
#pragma unroll
            for (int j = 0; j < 4; ++j) s[j] = *(const float4*)&sS[sr][sc + j * 4];
            float m = -1e30f;
#pragma unroll
            for (int j = 0; j < 4; ++j)
                m = fmaxf(m, fmaxf(fmaxf(s[j].x, s[j].y), fmaxf(s[j].z, s[j].w)));
            m = fmaxf(m, __shfl_xor(m, 1));
            m = fmaxf(m, __shfl_xor(m, 2));
            float m_old = sM[sr];
            float m_new = fmaxf(m_old, m);
            float sum = 0.f;
#pragma unroll
            for (int j = 0; j < 4; ++j) {
                s[j].x = __expf(s[j].x - m_new); s[j].y = __expf(s[j].y - m_new);
                s[j].z = __expf(s[j].z - m_new); s[j].w = __expf(s[j].w - m_new);
                sum += s[j].x + s[j].y + s[j].z + s[j].w;
                *(float4*)&sS[sr][sc + j * 4] = s[j];
            }
            sum += __shfl_xor(sum, 1);
            sum += __shfl_xor(sum, 2);
            if ((t & 3) == 0) {
                float alpha = __expf(m_old - m_new);
                sAl[sr] = alpha;
                sM[sr] = m_new;
                sL[sr] = sL[sr] * alpha + sum;
            }
        }
#pragma unroll
        for (int j = 0; j < 4; ++j) *(float4*)&sKV[lr][lq + j * 4] = vreg[j];
        __syncthreads();
#pragma unroll
        for (int i = 0; i < 4; ++i) {
            float al = sAl[rp + i];
            o_acc[i].x *= al; o_acc[i].y *= al; o_acc[i].z *= al; o_acc[i].w *= al;
        }
        for (int kk4 = 0; kk4 < 64; kk4 += 4) {
            float4 pv[4], vv[4];
#pragma unroll
            for (int i = 0; i < 4; ++i) pv[i] = *(const float4*)&sS[rp + i][kk4];
#pragma unroll
            for (int j = 0; j < 4; ++j) vv[j] = *(const float4*)&sKV[kk4 + j][d4];
#pragma unroll
            for (int i = 0; i < 4; ++i) {
                o_acc[i].x += pv[i].x * vv[0].x + pv[i].y * vv[1].x +
                              pv[i].z * vv[2].x + pv[i].w * vv[3].x;
                o_acc[i].y += pv[i].x * vv[0].y + pv[i].y * vv[1].y +
                              pv[i].z * vv[2].y + pv[i].w * vv[3].y;
                o_acc[i].z += pv[i].x * vv[0].z + pv[i].y * vv[1].z +
                              pv[i].z * vv[2].z + pv[i].w * vv[3].z;
                o_acc[i].w += pv[i].x * vv[0].w + pv[i].y * vv[1].w +
                              pv[i].z * vv[2].w + pv[i].w * vv[3].w;
            }
        }
    }
    __syncthreads();
#pragma unroll
    for (int i = 0; i < 4; ++i) {
        float inv = 1.0f / sL[rp + i];
        float4 o = o_acc[i];
        o.x *= inv; o.y *= inv; o.z *= inv; o.w *= inv;
        *(float4*)(ctx + (size_t)(b * cS + q0 + rp + i) * cH + h * cDH + d4) = o;
    }
}

__device__ __forceinline__ float block_reduce_sum(float v, float* red) {
#pragma unroll
    for (int o = 32; o; o >>= 1) v += __shfl_xor(v, o);
    __syncthreads();
    if ((threadIdx.x & 63) == 0) red[threadIdx.x >> 6] = v;
    __syncthreads();
    return red[0] + red[1] + red[2] + red[3];
}

// ---------------------------------------------------------------------------
// LN1 + LN2 + router, fp32 (selection-exact). Dense = four K-split partials.
__global__ __launch_bounds__(256) void ln_router_kernel(
    const float* __restrict__ dense0, const float* __restrict__ dense1,
    const float* __restrict__ dense2, const float* __restrict__ dense3,
    const float* __restrict__ resid,
    const float* __restrict__ g1, const float* __restrict__ b1,
    const float* __restrict__ g2, const float* __restrict__ b2,
    const float* __restrict__ Wr, const float* __restrict__ br,
    float* __restrict__ out, bf16* __restrict__ xlb,
    float* __restrict__ out_logits, float* __restrict__ wgt,
    int* __restrict__ counts, int* __restrict__ lists) {
    __shared__ float red[4];
    __shared__ float lred[4][8];
    const int t = blockIdx.x, tid = threadIdx.x;
    const size_t base = (size_t)t * cH;
    float v[3], s = 0.f;
#pragma unroll
    for (int i = 0; i < 3; ++i) {
        size_t ix = base + tid + 256 * i;
        v[i] = dense0[ix] + dense1[ix] + dense2[ix] + dense3[ix] + resid[ix];
        s += v[i];
    }
    const float mean = block_reduce_sum(s, red) * (1.0f / cH);
    float vs = 0.f;
#pragma unroll
    for (int i = 0; i < 3; ++i) { float d = v[i] - mean; vs += d * d; }
    const float rstd = rsqrtf(block_reduce_sum(vs, red) * (1.0f / cH) + 1e-12f);
    float a[3], s2 = 0.f;
#pragma unroll
    for (int i = 0; i < 3; ++i) {
        a[i] = (v[i] - mean) * rstd * g1[tid + 256 * i] + b1[tid + 256 * i];
        out[base + tid + 256 * i] = a[i];
        s2 += a[i];
    }
    const float mean2 = block_reduce_sum(s2, red) * (1.0f / cH);
    float vs2 = 0.f;
#pragma unroll
    for (int i = 0; i < 3; ++i) { float d = a[i] - mean2; vs2 += d * d; }
    const float rstd2 = rsqrtf(block_reduce_sum(vs2, red) * (1.0f / cH) + 1e-12f);
    float xl[3];
#pragma unroll
    for (int i = 0; i < 3; ++i) {
        xl[i] = (a[i] - mean2) * rstd2 * g2[tid + 256 * i] + b2[tid + 256 * i];
        xlb[base + tid + 256 * i] = (bf16)xl[i];
    }
    float lg[cE] = {};
#pragma unroll
    for (int i = 0; i < 3; ++i) {
        const float* wr = Wr + (size_t)(tid + 256 * i) * cE;
#pragma unroll
        for (int e = 0; e < cE; ++e) lg[e] += xl[i] * wr[e];
    }
#pragma unroll
    for (int e = 0; e < cE; ++e)
#pragma unroll
        for (int o = 32; o; o >>= 1) lg[e] += __shfl_xor(lg[e], o);
    if ((tid & 63) == 0)
#pragma unroll
        for (int e = 0; e < cE; ++e) lred[tid >> 6][e] = lg[e];
    __syncthreads();
    if (tid == 0) {
        float logits[cE];
#pragma unroll
        for (int e = 0; e < cE; ++e) {
            logits[e] = lred[0][e] + lred[1][e] + lred[2][e] + lred[3][e] + br[e];
            out_logits[(size_t)t * cE + e] = logits[e];
        }
        int i0 = 0;
        for (int e = 1; e < cE; ++e) if (logits[e] > logits[i0]) i0 = e;
        int i1 = (i0 == 0) ? 1 : 0;
        for (int e = 0; e < cE; ++e)
            if (e != i0 && logits[e] > logits[i1]) i1 = e;
        float e1 = __expf(logits[i1] - logits[i0]);
        float w0 = 1.0f / (1.0f + e1);
        float w1 = e1 * w0;
        wgt[t * 2 + 0] = w0;
        wgt[t * 2 + 1] = w1;
        int p0 = atomicAdd(&counts[i0], 1);
        lists[i0 * cT + p0] = t * 2 + 0;
        int p1 = atomicAdd(&counts[i1], 1);
        lists[i1 * cT + p1] = t * 2 + 1;
    }
}

// ---------------------------------------------------------------------------
// Expert up, 128x64 tile, BK=64 (two [.][32] sub-tiles), DOUBLE-BUFFERED LDS:
// stage(kk+64 -> buf^1) issued before compute(buf); single barrier per step
// drains loads that had the whole compute phase in flight. Bit-exact.
__global__ __launch_bounds__(256) void expert_up_mfma_kernel(
    const bf16* __restrict__ xlb,
    const bf16* __restrict__ WupT, const bf16* __restrict__ WnewT,
    const float* __restrict__ b_up, const float* __restrict__ b_new,
    const int* __restrict__ counts, const int* __restrict__ lists,
    bf16* __restrict__ act) {
    const int e = blockIdx.z;
    const int cnt = counts[e];
    const int m0 = blockIdx.y * 128;
    if (m0 >= cnt) return;
    const int n0 = blockIdx.x * 64;
    __shared__ short sA[2][8192], sB1[2][4096], sB2[2][4096];   // 64KB
    __shared__ int rowa[128];
    const int t = threadIdx.x;
    if (t < 128) {
        int idx = m0 + t;
        rowa[t] = (idx < cnt) ? lists[e * cT + idx] : -1;
    }
    __syncthreads();
    const int lane = t & 63, w = t >> 6;
    const int wm = (w >> 1) * 64, wn = (w & 1) * 32;
    const int rA0 = t >> 2, kc8 = (t & 3) * 8;
    int a0 = rowa[rA0], a1 = rowa[rA0 + 64];
    const bf16* gA0 = xlb + (size_t)(a0 < 0 ? 0 : (a0 >> 1)) * cH + kc8;
    const bf16* gA1 = xlb + (size_t)(a1 < 0 ? 0 : (a1 >> 1)) * cH + kc8;
    const bf16* B1 = WupT + (size_t)e * cI * cH;
    const bf16* B2 = WnewT + (size_t)e * cI * cH;
    const bf16* gB1 = B1 + (size_t)(n0 + rA0) * cH + kc8;
    const bf16* gB2 = B2 + (size_t)(n0 + rA0) * cH + kc8;
    // linear thread-order LDS dests (glds16 wave-uniform-base rule)
    auto stage = [&](int bi, int kk) {
        glds16(gA0 + kk,      &sA[bi][t * 8]);          // ks0 rows 0..63
        glds16(gA1 + kk,      &sA[bi][(t + 256) * 8]);  // ks0 rows 64..127
        glds16(gA0 + kk + 32, &sA[bi][(t + 512) * 8]);  // ks1 rows 0..63
        glds16(gA1 + kk + 32, &sA[bi][(t + 768) * 8]);  // ks1 rows 64..127
        glds16(gB1 + kk,      &sB1[bi][t * 8]);         // ks0
        glds16(gB1 + kk + 32, &sB1[bi][(t + 256) * 8]); // ks1
        glds16(gB2 + kk,      &sB2[bi][t * 8]);
        glds16(gB2 + kk + 32, &sB2[bi][(t + 256) * 8]);
    };
    f4v zero = {0.f, 0.f, 0.f, 0.f};
    f4v acc1[4][2], acc2[4][2];
#pragma unroll
    for (int i = 0; i < 4; ++i)
#pragma unroll
        for (int j = 0; j < 2; ++j) { acc1[i][j] = zero; acc2[i][j] = zero; }
    const int fr = lane & 15, kg = (lane >> 4) * 8;
    stage(0, 0);
    __syncthreads();
    int buf = 0;
    for (int kk = 0; kk < cH; kk += 64) {
        if (kk + 64 < cH) stage(buf ^ 1, kk + 64);   // prefetch under compute
#pragma unroll
        for (int ks = 0; ks < 2; ++ks) {
            const short* pA  = &sA[buf][ks * 4096];
            const short* pB1 = &sB1[buf][ks * 2048];
            const short* pB2 = &sB2[buf][ks * 2048];
            s8v af[4], bf1[2], bf2[2];
#pragma unroll
            for (int i = 0; i < 4; ++i)
                af[i] = *(const s8v*)(pA + (wm + i * 16 + fr) * 32 + kg);
#pragma unroll
            for (int j = 0; j < 2; ++j) {
                bf1[j] = *(const s8v*)(pB1 + (wn + j * 16 + fr) * 32 + kg);
                bf2[j] = *(const s8v*)(pB2 + (wn + j * 16 + fr) * 32 + kg);
            }
#pragma unroll
            for (int mi = 0; mi < 4; ++mi)
#pragma unroll
                for (int ni = 0; ni < 2; ++ni) {
                    acc1[mi][ni] = __builtin_amdgcn_mfma_f32_16x16x32_bf16(
                        af[mi], bf1[ni], acc1[mi][ni], 0, 0, 0);
                    acc2[mi][ni] = __builtin_amdgcn_mfma_f32_16x16x32_bf16(
                        af[mi], bf2[ni], acc2[mi][ni], 0, 0, 0);
                }
        }
        __syncthreads();   // drains prefetch (overlapped with compute above)
        buf ^= 1;
    }
    const int cn = lane & 15, rq = (lane >> 4) * 4;
#pragma unroll
    for (int mi = 0; mi < 4; ++mi)
#pragma unroll
        for (int r = 0; r < 4; ++r) {
            int ml = wm + mi * 16 + rq + r;
            int a = rowa[ml];
            if (a < 0) continue;
            bf16* orow = act + (size_t)a * cI + n0 + wn;
#pragma unroll
            for (int ni = 0; ni < 2; ++ni) {
                int nl = ni * 16 + cn;
                float up = acc1[mi][ni][r] + b_up[e * cI + n0 + wn + nl];
                float nw = acc2[mi][ni][r] + b_new[e * cI + n0 + wn + nl];
                float g = 0.5f * up * (1.0f + erff(up * 0.70710678118654752f));
                orow[nl] = (bf16)(g * nw);
            }
        }
}

// Expert down (128x128), BK=64, DOUBLE-BUFFERED LDS (same 2-phase template).
__global__ __launch_bounds__(256) void expert_down_mfma_kernel(
    const bf16* __restrict__ act, const bf16* __restrict__ WdownT,
    const float* __restrict__ b_down,
    const int* __restrict__ counts, const int* __restrict__ lists,
    const float* __restrict__ wgt, float* __restrict__ out) {
    const int e = blockIdx.z;
    const int cnt = counts[e];
    const int m0 = blockIdx.y * 128;
    if (m0 >= cnt) return;
    const int n0 = blockIdx.x * 128;
    __shared__ short sA[2][8192], sB[2][8192];   // 64KB
    __shared__ int rowa[128];
    const int t = threadIdx.x;
    if (t < 128) {
        int idx = m0 + t;
        rowa[t] = (idx < cnt) ? lists[e * cT + idx] : -1;
    }
    __syncthreads();
    const int lane = t & 63, w = t >> 6;
    const int wm = (w >> 1) * 64, wn = (w & 1) * 64;
    const int rA0 = t >> 2, kc8 = (t & 3) * 8;
    int a0 = rowa[rA0], a1 = rowa[rA0 + 64];
    const bf16* gA0 = act + (size_t)(a0 < 0 ? 0 : a0) * cI + kc8;
    const bf16* gA1 = act + (size_t)(a1 < 0 ? 0 : a1) * cI + kc8;
    const bf16* BT = WdownT + (size_t)e * cH * cI;
    const bf16* gB0 = BT + (size_t)(n0 + rA0) * cI + kc8;
    const bf16* gB1 = BT + (size_t)(n0 + rA0 + 64) * cI + kc8;
    auto stage = [&](int bi, int kk) {
        glds16(gA0 + kk,      &sA[bi][t * 8]);
        glds16(gA1 + kk,      &sA[bi][(t + 256) * 8]);
        glds16(gA0 + kk + 32, &sA[bi][(t + 512) * 8]);
        glds16(gA1 + kk + 32, &sA[bi][(t + 768) * 8]);
        glds16(gB0 + kk,      &sB[bi][t * 8]);
        glds16(gB1 + kk,      &sB[bi][(t + 256) * 8]);
        glds16(gB0 + kk + 32, &sB[bi][(t + 512) * 8]);
        glds16(gB1 + kk + 32, &sB[bi][(t + 768) * 8]);
    };
    f4v zero = {0.f, 0.f, 0.f, 0.f};
    f4v acc[4][4];
#pragma unroll
    for (int i = 0; i < 4; ++i)
#pragma unroll
        for (int j = 0; j < 4; ++j) acc[i][j] = zero;
    const int fr = lane & 15, kg = (lane >> 4) * 8;
    stage(0, 0);
    __syncthreads();
    int buf = 0;
    for (int kk = 0; kk < cI; kk += 64) {
        if (kk + 64 < cI) stage(buf ^ 1, kk + 64);   // prefetch under compute
#pragma unroll
        for (int ks = 0; ks < 2; ++ks) {
            const short* pA = &sA[buf][ks * 4096];
            const short* pB = &sB[buf][ks * 4096];
            s8v af[4], bf[4];
#pragma unroll
            for (int i = 0; i < 4; ++i)
                af[i] = *(const s8v*)(pA + (wm + i * 16 + fr) * 32 + kg);
#pragma unroll
            for (int i = 0; i < 4; ++i)
                bf[i] = *(const s8v*)(pB + (wn + i * 16 + fr) * 32 + kg);
#pragma unroll
            for (int mi = 0; mi < 4; ++mi)
#pragma unroll
                for (int ni = 0; ni < 4; ++ni)
                    acc[mi][ni] = __builtin_amdgcn_mfma_f32_16x16x32_bf16(
                        af[mi], bf[ni], acc[mi][ni], 0, 0, 0);
        }
        __syncthreads();
        buf ^= 1;
    }
    const int cn = lane & 15, rq = (lane >> 4) * 4;
#pragma unroll
    for (int mi = 0; mi < 4; ++mi)
#pragma unroll
        for (int r = 0; r < 4; ++r) {
            int ml = wm + mi * 16 + rq + r;
            int a = rowa[ml];
            if (a < 0) continue;
            int token = a >> 1;
            float wv = wgt[a];
#pragma unroll
            for (int ni = 0; ni < 4; ++ni) {
                int n = n0 + wn + ni * 16 + cn;
                atomicAdd(&out[(size_t)token * cH + n],
                          wv * (acc[mi][ni][r] + b_down[e * cH + n]));
            }
        }
}

// ---------------------------------------------------------------------------
extern "C" void kernel_launch(void* const* d_in, const int* in_sizes, int n_in,
                              void* d_out, int out_size, void* d_ws, size_t ws_size,
                              hipStream_t stream) {
    const float* x      = (const float*)d_in[0];
    const float* Wq     = (const float*)d_in[1];
    const float* bq     = (const float*)d_in[2];
    const float* Wk     = (const float*)d_in[3];
    const float* bk     = (const float*)d_in[4];
    const float* Wv     = (const float*)d_in[5];
    const float* bv     = (const float*)d_in[6];
    const float* Wo     = (const float*)d_in[7];
    const float* bo     = (const float*)d_in[8];
    const float* ln1g   = (const float*)d_in[9];
    const float* ln1b   = (const float*)d_in[10];
    const float* ln2g   = (const float*)d_in[11];
    const float* ln2b   = (const float*)d_in[12];
    const float* Wr     = (const float*)d_in[13];
    const float* br     = (const float*)d_in[14];
    const float* W_up   = (const float*)d_in[15];
    const float* b_up   = (const float*)d_in[16];
    const float* W_new  = (const float*)d_in[17];
    const float* b_new  = (const float*)d_in[18];
    const float* W_down = (const float*)d_in[19];
    const float* b_down = (const float*)d_in[20];

    float* out = (float*)d_out;
    float* ws  = (float*)d_ws;

    bf16* WupT   = (bf16*)(ws + OFF_WUP_T);
    bf16* WnewT  = (bf16*)(ws + OFF_WNEW_T);
    bf16* WdownT = (bf16*)(ws + OFF_WDOWN_T);
    float* q     = ws + OFF_QKV;
    float* k     = ws + OFF_QKV + TH;
    float* v     = ws + OFF_QKV + 2 * TH;
    float* tmp   = ws + OFF_QKV + 3 * TH;
    bf16* act    = (bf16*)(ws + OFF_QKV);   // aliases q/k/v/tmp (dead by then)
    float* ctx   = ws + OFF_CTX;
    bf16* xlb    = (bf16*)(ws + OFF_XLB);
    float* wgt   = ws + OFF_WGT;
    int* counts  = (int*)(ws + OFF_COUNTS);
    int* lists   = (int*)(ws + OFF_LISTS);

    init_counts_kernel<<<1, 64, 0, stream>>>(counts);

    // expert weight transpose+convert
    transpose_bf16_kernel<<<dim3(48, 12, cE), 256, 0, stream>>>(W_up, WupT, cH, cI);
    transpose_bf16_kernel<<<dim3(48, 12, cE), 256, 0, stream>>>(W_new, WnewT, cH, cI);
    transpose_bf16_kernel<<<dim3(12, 48, cE), 256, 0, stream>>>(W_down, WdownT, cI, cH);

    // fp32 pre-router path (selection-exact), round-11 config:
    // 32x256 s_load body + QKV ksplit2 (partials q1->tmp, k1->ctx, v1->out).
    gemm_qkv_kernel<<<dim3(3, 128, 6), 256, 0, stream>>>(
        x, Wq, Wk, Wv, bq, bk, bv, q, k, v, tmp, ctx, out);
    reduce_qkv_kernel<<<2048, 256, 0, stream>>>(q, tmp, v, out);
    attn_kernel<<<dim3(cS / 64, cNH, cB), 256, 0, stream>>>(q, k, v, ctx);
    // Wo ksplit=4: partials into dead q,k,v,tmp; summed inside ln_router
    gemm_wo_kernel<<<dim3(3, 128, 4), 256, 0, stream>>>(
        ctx, Wo, bo, q, k, v, tmp);
    ln_router_kernel<<<cT, 256, 0, stream>>>(
        q, k, v, tmp, x, ln1g, ln1b, ln2g, ln2b, Wr, br,
        out, xlb, out + TH, wgt, counts, lists);

    // bf16 MFMA experts (scatter-add into out), BK=64 + LDS double-buffer
    expert_up_mfma_kernel<<<dim3(cI / 64, cT / 128, cE), 256, 0, stream>>>(
        xlb, WupT, WnewT, b_up, b_new, counts, lists, act);
    expert_down_mfma_kernel<<<dim3(cH / 128, cT / 128, cE), 256, 0, stream>>>(
        act, WdownT, b_down, counts, lists, wgt, out);
}